// Round 15
// baseline (305.264 us; speedup 1.0000x reference)
//
#include <hip/hip_runtime.h>
#include <hip/hip_bf16.h>
#include <stdint.h>

#define BATCH   2
#define SEQLEN  4096
#define DMODEL  768
#define DSTATE  64
#define DCONV   4
#define HEADDIM 128
#define NHEADS  12
#define DINNER  1536
#define DINPROJ 3212
#define CONVDIM 1664
#define DXBC    1676            // CONVDIM + NHEADS (xBC + dt columns)
#define NPAD1   3328            // 26*128, padded rows of W_in (bf16 copy)
#define ROWS    (BATCH*SEQLEN)  // 8192
#define CHUNK   64
#define NCHUNK  (SEQLEN/CHUNK)  // 64
#define CROWS   8               // rows per conv block
#define TBUF    4096            // GEMM LDS buffer stride (elements) = 128*32

typedef __bf16 bf16x8 __attribute__((ext_vector_type(8)));
typedef float  f32x4  __attribute__((ext_vector_type(4)));

__device__ __forceinline__ f32x4 splat4(float v) { return (f32x4){v, v, v, v}; }

__device__ __forceinline__ void load_lds16(const void* g, void* l) {
    __builtin_amdgcn_global_load_lds(
        (const __attribute__((address_space(1))) unsigned int*)g,
        (__attribute__((address_space(3))) unsigned int*)l, 16, 0, 0);
}

// ---------------- conversion kernels ----------------
__global__ void cvt_bf16_kernel(const float* __restrict__ src,
                                __hip_bfloat16* __restrict__ dst, int n) {
    int i = (blockIdx.x * blockDim.x + threadIdx.x) * 4;
    if (i + 3 < n) {
        float4 v = *(const float4*)(src + i);
        dst[i + 0] = __float2bfloat16(v.x);
        dst[i + 1] = __float2bfloat16(v.y);
        dst[i + 2] = __float2bfloat16(v.z);
        dst[i + 3] = __float2bfloat16(v.w);
    } else {
        for (; i < n; ++i) dst[i] = __float2bfloat16(src[i]);
    }
}

__global__ void padw1_kernel(const float* __restrict__ src,
                             __hip_bfloat16* __restrict__ dst) {
    int i = blockIdx.x * blockDim.x + threadIdx.x;
    if (i >= NPAD1 * DMODEL) return;
    int r = i / DMODEL;
    float v = (r < DINPROJ) ? src[i] : 0.f;
    dst[i] = __float2bfloat16(v);
}

// ---------------- bf16 MFMA GEMM (double-buffered, swizzled LDS) ------------
__global__ __launch_bounds__(256) void gemm_bf16_nt(
    const __hip_bfloat16* __restrict__ A,
    const __hip_bfloat16* __restrict__ Bt,
    float* __restrict__ C,
    int M, int Nreal, int K, int ldc)
{
    __shared__ __align__(16) __hip_bfloat16 As[2 * TBUF];
    __shared__ __align__(16) __hip_bfloat16 Bs[2 * TBUF];
    const int tid  = threadIdx.x;
    const int lane = tid & 63;
    const int wave = tid >> 6;
    const int wm   = wave >> 1;
    const int wn   = wave & 1;
    const int tm   = blockIdx.x * 128;
    const int tn   = blockIdx.y * 128;

    f32x4 acc[4][4] = {};

    const int lrow = tid >> 2;
    const int lk8s = ((tid & 3) * 8) ^ (((tid >> 3) & 3) << 3);
    const __hip_bfloat16* gA0 = A  + (size_t)(tm + lrow)      * K + lk8s;
    const __hip_bfloat16* gA1 = A  + (size_t)(tm + lrow + 64) * K + lk8s;
    const __hip_bfloat16* gB0 = Bt + (size_t)(tn + lrow)      * K + lk8s;
    const __hip_bfloat16* gB1 = Bt + (size_t)(tn + lrow + 64) * K + lk8s;

    const int fr  = lane & 15;
    const int fks = ((lane >> 4) * 8) ^ (((lane >> 1) & 3) << 3);

    load_lds16(gA0, As + tid * 8);
    load_lds16(gA1, As + tid * 8 + 2048);
    load_lds16(gB0, Bs + tid * 8);
    load_lds16(gB1, Bs + tid * 8 + 2048);
    __syncthreads();

    int bufo = 0;
    for (int kk = 0; kk < K; kk += 32) {
        const int nbufo = bufo ^ TBUF;
        if (kk + 32 < K) {
            load_lds16(gA0 + kk + 32, As + nbufo + tid * 8);
            load_lds16(gA1 + kk + 32, As + nbufo + tid * 8 + 2048);
            load_lds16(gB0 + kk + 32, Bs + nbufo + tid * 8);
            load_lds16(gB1 + kk + 32, Bs + nbufo + tid * 8 + 2048);
        }
        bf16x8 af[4], bfr[4];
#pragma unroll
        for (int i = 0; i < 4; ++i) {
            af[i]  = *(const bf16x8*)(As + bufo + (wm * 64 + i * 16 + fr) * 32 + fks);
            bfr[i] = *(const bf16x8*)(Bs + bufo + (wn * 64 + i * 16 + fr) * 32 + fks);
        }
#pragma unroll
        for (int mi = 0; mi < 4; ++mi)
#pragma unroll
            for (int ni = 0; ni < 4; ++ni)
                acc[mi][ni] = __builtin_amdgcn_mfma_f32_16x16x32_bf16(
                    af[mi], bfr[ni], acc[mi][ni], 0, 0, 0);
        __syncthreads();
        bufo = nbufo;
    }

    const int rq = (lane >> 4) * 4;
#pragma unroll
    for (int mi = 0; mi < 4; ++mi) {
#pragma unroll
        for (int ni = 0; ni < 4; ++ni) {
            int col = tn + wn * 64 + ni * 16 + fr;
            if (col < Nreal) {
                size_t rbase = (size_t)(tm + wm * 64 + mi * 16 + rq) * ldc + col;
#pragma unroll
                for (int j = 0; j < 4; ++j)
                    C[rbase + (size_t)j * ldc] = acc[mi][ni][j];
            }
        }
    }
}

// ---------------- GEMM1 fused (double-buffered, swizzled, tile-routed) ------
__global__ __launch_bounds__(256) void gemm1_fused(
    const __hip_bfloat16* __restrict__ A,
    const __hip_bfloat16* __restrict__ Bt,
    float* __restrict__ Cz,     // (ROWS, DINNER)
    float* __restrict__ Cx)     // (ROWS, DXBC)
{
    __shared__ __align__(16) __hip_bfloat16 As[2 * TBUF];
    __shared__ __align__(16) __hip_bfloat16 Bs[2 * TBUF];
    const int tid  = threadIdx.x;
    const int lane = tid & 63;
    const int wave = tid >> 6;
    const int wm   = wave >> 1;
    const int wn   = wave & 1;
    const int tm   = blockIdx.x * 128;
    const int tn   = blockIdx.y * 128;
    const int K    = DMODEL;

    float* Co;
    int ldc2, cb, nb;
    if (tn < DINNER) { Co = Cz; ldc2 = DINNER; cb = tn;          nb = DINNER; }
    else             { Co = Cx; ldc2 = DXBC;   cb = tn - DINNER; nb = DXBC;   }

    f32x4 acc[4][4] = {};

    const int lrow = tid >> 2;
    const int lk8s = ((tid & 3) * 8) ^ (((tid >> 3) & 3) << 3);
    const __hip_bfloat16* gA0 = A  + (size_t)(tm + lrow)      * K + lk8s;
    const __hip_bfloat16* gA1 = A  + (size_t)(tm + lrow + 64) * K + lk8s;
    const __hip_bfloat16* gB0 = Bt + (size_t)(tn + lrow)      * K + lk8s;
    const __hip_bfloat16* gB1 = Bt + (size_t)(tn + lrow + 64) * K + lk8s;

    const int fr  = lane & 15;
    const int fks = ((lane >> 4) * 8) ^ (((lane >> 1) & 3) << 3);

    load_lds16(gA0, As + tid * 8);
    load_lds16(gA1, As + tid * 8 + 2048);
    load_lds16(gB0, Bs + tid * 8);
    load_lds16(gB1, Bs + tid * 8 + 2048);
    __syncthreads();

    int bufo = 0;
    for (int kk = 0; kk < K; kk += 32) {
        const int nbufo = bufo ^ TBUF;
        if (kk + 32 < K) {
            load_lds16(gA0 + kk + 32, As + nbufo + tid * 8);
            load_lds16(gA1 + kk + 32, As + nbufo + tid * 8 + 2048);
            load_lds16(gB0 + kk + 32, Bs + nbufo + tid * 8);
            load_lds16(gB1 + kk + 32, Bs + nbufo + tid * 8 + 2048);
        }
        bf16x8 af[4], bfr[4];
#pragma unroll
        for (int i = 0; i < 4; ++i) {
            af[i]  = *(const bf16x8*)(As + bufo + (wm * 64 + i * 16 + fr) * 32 + fks);
            bfr[i] = *(const bf16x8*)(Bs + bufo + (wn * 64 + i * 16 + fr) * 32 + fks);
        }
#pragma unroll
        for (int mi = 0; mi < 4; ++mi)
#pragma unroll
            for (int ni = 0; ni < 4; ++ni)
                acc[mi][ni] = __builtin_amdgcn_mfma_f32_16x16x32_bf16(
                    af[mi], bfr[ni], acc[mi][ni], 0, 0, 0);
        __syncthreads();
        bufo = nbufo;
    }

    const int rq = (lane >> 4) * 4;
#pragma unroll
    for (int mi = 0; mi < 4; ++mi) {
#pragma unroll
        for (int ni = 0; ni < 4; ++ni) {
            int col = cb + wn * 64 + ni * 16 + fr;
            if (col < nb) {
                size_t rbase = (size_t)(tm + wm * 64 + mi * 16 + rq) * ldc2 + col;
#pragma unroll
                for (int j = 0; j < 4; ++j)
                    Co[rbase + (size_t)j * ldc2] = acc[mi][ni][j];
            }
        }
    }
}

// ---------------- depthwise causal conv: 8 rows/block, rolling window -------
__global__ void conv_kernel(const float* __restrict__ xbcdt,
                            const float* __restrict__ convw,
                            const float* __restrict__ convb,
                            float* __restrict__ xbuf,
                            float* __restrict__ Bm,
                            float* __restrict__ Cm)
{
    int c = blockIdx.x * 256 + threadIdx.x;
    if (c >= CONVDIM) return;
    size_t row0 = (size_t)blockIdx.y * CROWS;
    int l0 = (int)(row0 & (SEQLEN - 1));
    float w0 = convw[c * 4 + 0];
    float w1 = convw[c * 4 + 1];
    float w2 = convw[c * 4 + 2];
    float w3 = convw[c * 4 + 3];
    float bias = convb[c];
    const float* src = xbcdt + row0 * DXBC + c;
    float x0 = (l0 >= 3) ? src[-3 * DXBC] : 0.f;
    float x1 = (l0 >= 2) ? src[-2 * DXBC] : 0.f;
    float x2 = (l0 >= 1) ? src[-1 * DXBC] : 0.f;
#pragma unroll
    for (int r = 0; r < CROWS; ++r) {
        float x3 = src[(size_t)r * DXBC];
        float acc = bias + x0 * w0 + x1 * w1 + x2 * w2 + x3 * w3;
        float v = acc / (1.f + __expf(-acc));
        size_t row = row0 + r;
        if (c < DINNER)               xbuf[row * DINNER + c] = v;
        else if (c < DINNER + DSTATE) Bm[row * DSTATE + (c - DINNER)] = v;
        else                          Cm[row * DSTATE + (c - DINNER - DSTATE)] = v;
        x0 = x1; x1 = x2; x2 = x3;
    }
}

// ---------------- dt softplus + dA ----------------
__global__ void dt_kernel(const float* __restrict__ xbcdt,
                          const float* __restrict__ dt_bias,
                          const float* __restrict__ A_log,
                          float* __restrict__ dtb, float* __restrict__ dAb)
{
    int i = blockIdx.x * 256 + threadIdx.x;
    if (i >= ROWS * NHEADS) return;
    int row = i / NHEADS, h = i - row * NHEADS;
    float v = xbcdt[(size_t)row * DXBC + CONVDIM + h] + dt_bias[h];
    float dt = (v > 20.f) ? v : log1pf(__expf(v));
    float A = -__expf(A_log[h]);
    dtb[i] = dt;
    dAb[i] = __expf(dt * A);
}

// ======== chunk state kernel: thread owns 4p x 8n (256 thr, no reduce) ======
__global__ __launch_bounds__(256) void chunk_state_f32(
    const float* __restrict__ xbuf, const float* __restrict__ Bm,
    const float* __restrict__ dtb, const float* __restrict__ dAb,
    float* __restrict__ Sloc, float* __restrict__ Pk)
{
    const int blk = blockIdx.x;
    const int k   = blk % NCHUNK;
    const int bh  = blk / NCHUNK;
    const int h   = bh % NHEADS;
    const int b   = bh / NHEADS;
    const int tid = threadIdx.x;
    const int pg  = tid >> 3;
    const int n0  = (tid & 7) * 8;
    const size_t row0 = (size_t)b * SEQLEN + k * CHUNK;
    const float* xbase = xbuf + (row0 * NHEADS + h) * HEADDIM + pg * 4;

    __shared__ __align__(16) float lB[CHUNK][DSTATE];    // 16 KB
    __shared__ float lDA[CHUNK];
    __shared__ float ldt[CHUNK];

    for (int i = tid; i < CHUNK * DSTATE / 4; i += 256)
        ((float4*)&lB[0][0])[i] = ((const float4*)(Bm + row0 * DSTATE))[i];
    if (tid < CHUNK) {
        lDA[tid] = dAb[(row0 + tid) * NHEADS + h];
        ldt[tid] = dtb[(row0 + tid) * NHEADS + h];
    }
    __syncthreads();

    f32x4 s4[4][2] = {};
    f32x4 xt0[4], xt1[4];

#pragma unroll
    for (int tt = 0; tt < 4; ++tt)
        xt0[tt] = *(const f32x4*)(xbase + (size_t)tt * (NHEADS * HEADDIM));

#pragma unroll
    for (int tile = 0; tile < 16; ++tile) {
        f32x4* cur = (tile & 1) ? xt1 : xt0;
        f32x4* nxt = (tile & 1) ? xt0 : xt1;
        if (tile < 15) {
#pragma unroll
            for (int tt = 0; tt < 4; ++tt)
                nxt[tt] = *(const f32x4*)(xbase +
                    (size_t)((tile + 1) * 4 + tt) * (NHEADS * HEADDIM));
        }
#pragma unroll
        for (int tt = 0; tt < 4; ++tt) {
            int t = tile * 4 + tt;
            f32x4 da4 = splat4(lDA[t]);
            float dtv = ldt[t];
            f32x4 bv0 = *(const f32x4*)&lB[t][n0];
            f32x4 bv1 = *(const f32x4*)&lB[t][n0 + 4];
#pragma unroll
            for (int pl = 0; pl < 4; ++pl) {
                f32x4 dtx = splat4(dtv * cur[tt][pl]);
                s4[pl][0] = s4[pl][0] * da4 + dtx * bv0;
                s4[pl][1] = s4[pl][1] * da4 + dtx * bv1;
            }
        }
    }

    const size_t kbase = (size_t)(bh * NCHUNK + k) * (HEADDIM * DSTATE);
#pragma unroll
    for (int pl = 0; pl < 4; ++pl) {
        size_t a = kbase + (size_t)(pg * 4 + pl) * DSTATE + n0;
        *(f32x4*)(Sloc + a)     = s4[pl][0];
        *(f32x4*)(Sloc + a + 4) = s4[pl][1];
    }

    if (tid == 0) {
        float pr = 1.f;
#pragma unroll 8
        for (int t = 0; t < CHUNK; ++t) pr *= lDA[t];
        Pk[bh * NCHUNK + k] = pr;
    }
}

// ---------------- scan phase 2: inter-chunk prefix (in-place F -> S_init) --
__global__ __launch_bounds__(256) void scan_phase2(
    float* __restrict__ Sloc, const float* __restrict__ Pk)
{
    int bh = blockIdx.x >> 5;
    int eo = (blockIdx.x & 31) * 256 + threadIdx.x;
    __shared__ float lP[NCHUNK];
    if (threadIdx.x < NCHUNK) lP[threadIdx.x] = Pk[bh * NCHUNK + threadIdx.x];
    __syncthreads();
    float s = 0.f;
    size_t base = (size_t)bh * NCHUNK * 8192 + eo;
#pragma unroll 8
    for (int k = 0; k < NCHUNK; ++k) {
        size_t a = base + (size_t)k * 8192;
        float f = Sloc[a];
        Sloc[a] = s;
        s = s * lP[k] + f;
    }
}

// ======== chunk y kernel: pair of chunks, 32-step WINDOWED B/C staging ======
// 256 thr; sub = tid>>7 owns chunk kp*2+sub; thread = 4p x 16n.
// LDS holds only a 32-step window of B/C for both chunks (33 KB -> 3 blk/CU).
__global__ __launch_bounds__(256) void chunk_y_f32(
    const float* __restrict__ xbuf, const float* __restrict__ Bm,
    const float* __restrict__ Cm, const float* __restrict__ dtb,
    const float* __restrict__ dAb, const float* __restrict__ Dp,
    const float* __restrict__ Sini, float* __restrict__ ybuf)
{
    const int blk = blockIdx.x;                 // 0 .. 767
    const int kp  = blk % (NCHUNK / 2);
    const int bh  = blk / (NCHUNK / 2);
    const int h   = bh % NHEADS;
    const int b   = bh / NHEADS;
    const int tid = threadIdx.x;
    const int sub = tid >> 7;                   // which chunk of the pair
    const int t2  = tid & 127;
    const int pg  = t2 >> 2;                    // p = pg*4..+3
    const int q   = t2 & 3;
    const int n0  = q * 16;
    const size_t prow0 = (size_t)b * SEQLEN + (size_t)kp * 2 * CHUNK;
    const size_t row0  = prow0 + (size_t)sub * CHUNK;
    const float* xbase = xbuf + (row0 * NHEADS + h) * HEADDIM + pg * 4;
    float* ybase = ybuf + (row0 * NHEADS + h) * HEADDIM + pg * 4;

    __shared__ __align__(16) float lB[64][DSTATE];   // 16 KB: 2 subs x 32-step window
    __shared__ __align__(16) float lC[64][DSTATE];   // 16 KB
    __shared__ float lDA[2 * CHUNK];
    __shared__ float ldt[2 * CHUNK];

    if (tid < 2 * CHUNK) {
        lDA[tid] = dAb[(prow0 + tid) * NHEADS + h];
        ldt[tid] = dtb[(prow0 + tid) * NHEADS + h];
    }

    // seed 4p x 16n states from S_init (f32) for this half's chunk
    f32x4 s4[4][4];
    const size_t kbase = (size_t)(bh * NCHUNK + kp * 2 + sub) * (HEADDIM * DSTATE);
#pragma unroll
    for (int pl = 0; pl < 4; ++pl) {
        size_t a = kbase + (size_t)(pg * 4 + pl) * DSTATE + n0;
#pragma unroll
        for (int nq = 0; nq < 4; ++nq)
            s4[pl][nq] = *(const f32x4*)(Sini + a + nq * 4);
    }
    const float dph = Dp[h];

#pragma unroll
    for (int w = 0; w < 2; ++w) {
        // stage window w: rows [w*32, w*32+32) of BOTH chunks (coalesced f4)
        for (int i = tid; i < 64 * DSTATE / 4; i += 256) {
            int r  = i >> 4;                     // 0..63 (sub*32 + local row)
            int c4 = i & 15;
            size_t gr = prow0 + (size_t)(r >> 5) * CHUNK + w * 32 + (r & 31);
            ((float4*)&lB[r][0])[c4] = ((const float4*)(Bm + gr * DSTATE))[c4];
            ((float4*)&lC[r][0])[c4] = ((const float4*)(Cm + gr * DSTATE))[c4];
        }
        __syncthreads();

        f32x4 xt0[4], xt1[4];
#pragma unroll
        for (int tt = 0; tt < 4; ++tt)
            xt0[tt] = *(const f32x4*)(xbase + (size_t)(w * 32 + tt) * (NHEADS * HEADDIM));

#pragma unroll
        for (int tile = 0; tile < 8; ++tile) {
            f32x4* cur = (tile & 1) ? xt1 : xt0;
            f32x4* nxt = (tile & 1) ? xt0 : xt1;
            if (tile < 7) {
#pragma unroll
                for (int tt = 0; tt < 4; ++tt)
                    nxt[tt] = *(const f32x4*)(xbase +
                        (size_t)(w * 32 + (tile + 1) * 4 + tt) * (NHEADS * HEADDIM));
            }
#pragma unroll
            for (int tt = 0; tt < 4; ++tt) {
                int t  = w * 32 + tile * 4 + tt;     // step within chunk
                int tr = sub * 32 + tile * 4 + tt;   // LDS window row
                f32x4 da4 = splat4(lDA[sub * CHUNK + t]);
                float dtv = ldt[sub * CHUNK + t];
                f32x4 bv0 = *(const f32x4*)&lB[tr][n0];
                f32x4 bv1 = *(const f32x4*)&lB[tr][n0 + 4];
                f32x4 bv2 = *(const f32x4*)&lB[tr][n0 + 8];
                f32x4 bv3 = *(const f32x4*)&lB[tr][n0 + 12];
                f32x4 cv0 = *(const f32x4*)&lC[tr][n0];
                f32x4 cv1 = *(const f32x4*)&lC[tr][n0 + 4];
                f32x4 cv2 = *(const f32x4*)&lC[tr][n0 + 8];
                f32x4 cv3 = *(const f32x4*)&lC[tr][n0 + 12];
                float yr[4];
#pragma unroll
                for (int pl = 0; pl < 4; ++pl) {
                    f32x4 dtx = splat4(dtv * cur[tt][pl]);
                    f32x4 v0 = s4[pl][0] * da4 + dtx * bv0;
                    f32x4 v1 = s4[pl][1] * da4 + dtx * bv1;
                    f32x4 v2 = s4[pl][2] * da4 + dtx * bv2;
                    f32x4 v3 = s4[pl][3] * da4 + dtx * bv3;
                    s4[pl][0] = v0; s4[pl][1] = v1; s4[pl][2] = v2; s4[pl][3] = v3;
                    f32x4 y4 = cv0 * v0 + cv1 * v1 + cv2 * v2 + cv3 * v3;
                    float y = (y4[0] + y4[1]) + (y4[2] + y4[3]);
                    y += __shfl_xor(y, 1);   // quad_perm DPP
                    y += __shfl_xor(y, 2);   // quad_perm DPP
                    yr[pl] = y;
                }
                if (q == 0) {
                    f32x4 wv = {yr[0] + dph * cur[tt][0], yr[1] + dph * cur[tt][1],
                                yr[2] + dph * cur[tt][2], yr[3] + dph * cur[tt][3]};
                    *(f32x4*)(ybase + (size_t)t * (NHEADS * HEADDIM)) = wv;
                }
            }
        }
        if (w == 0) __syncthreads();   // protect window before restage
    }
}

// ---------------- fallback: original monolithic scan ------------------------
#define NT 64
__global__ __launch_bounds__(256) void scan_kernel(
    const float* __restrict__ xbuf, const float* __restrict__ Bm,
    const float* __restrict__ Cm, const float* __restrict__ dtb,
    const float* __restrict__ dAb, const float* __restrict__ Dp,
    float* __restrict__ ybuf)
{
    int blk = blockIdx.x;
    int ps = blk & 7;
    int h  = (blk >> 3) % NHEADS;
    int b  = blk / (NHEADS * 8);
    int p0 = ps * 16;
    int tid = threadIdx.x;
    int pl  = tid >> 4;
    int n0  = (tid & 15) * 4;

    __shared__ __align__(16) float lB[NT][64];
    __shared__ __align__(16) float lC[NT][64];
    __shared__ __align__(16) float lDtx[NT][16];
    __shared__ float lDA[NT];
    __shared__ float lY[NT][16];

    float s0 = 0.f, s1 = 0.f, s2 = 0.f, s3 = 0.f;
    float dph = Dp[h];
    size_t rowbase = (size_t)b * SEQLEN;

    for (int t0 = 0; t0 < SEQLEN; t0 += NT) {
        for (int i = tid; i < NT * 64 / 4; i += 256) {
            ((float4*)&lB[0][0])[i] = ((const float4*)Bm)[(rowbase + t0) * 16 + i];
            ((float4*)&lC[0][0])[i] = ((const float4*)Cm)[(rowbase + t0) * 16 + i];
        }
        for (int i = tid; i < NT * 16; i += 256) {
            int t = i >> 4, pp = i & 15;
            size_t r = rowbase + t0 + t;
            lDtx[t][pp] = dtb[r * NHEADS + h] * xbuf[(r * NHEADS + h) * HEADDIM + p0 + pp];
        }
        if (tid < NT) lDA[tid] = dAb[(rowbase + t0 + tid) * NHEADS + h];
        __syncthreads();

        for (int t = 0; t < NT; ++t) {
            float da  = lDA[t];
            float dtx = lDtx[t][pl];
            const float* bp = &lB[t][n0];
            const float* cp = &lC[t][n0];
            s0 = s0 * da + dtx * bp[0];
            s1 = s1 * da + dtx * bp[1];
            s2 = s2 * da + dtx * bp[2];
            s3 = s3 * da + dtx * bp[3];
            float part = s0 * cp[0] + s1 * cp[1] + s2 * cp[2] + s3 * cp[3];
            part += __shfl_xor(part, 1);
            part += __shfl_xor(part, 2);
            part += __shfl_xor(part, 4);
            part += __shfl_xor(part, 8);
            if ((tid & 15) == 0) lY[t][pl] = part;
        }
        __syncthreads();

        for (int i = tid; i < NT * 16; i += 256) {
            int t = i >> 4, pp = i & 15;
            size_t r = rowbase + t0 + t;
            size_t gi = (r * NHEADS + h) * HEADDIM + p0 + pp;
            ybuf[gi] = lY[t][pp] + dph * xbuf[gi];
        }
        __syncthreads();
    }
}

// ---------------- gate (y * silu(z)) + RMSNorm -> bf16 (float2 path) --------
__global__ __launch_bounds__(256) void gate_rms_kernel(
    const float* __restrict__ ybuf, const float* __restrict__ zbuf,
    const float* __restrict__ norm_w, __hip_bfloat16* __restrict__ gbf)
{
    int row = blockIdx.x;
    int tid = threadIdx.x;
    const float2* y2 = (const float2*)(ybuf + (size_t)row * DINNER);
    const float2* z2 = (const float2*)(zbuf + (size_t)row * DINNER);
    const float2* nw2 = (const float2*)norm_w;
    float g[6];
    float ss = 0.f;
#pragma unroll
    for (int j = 0; j < 3; ++j) {
        int idx = tid + j * 256;
        float2 yy = y2[idx];
        float2 zz = z2[idx];
        float g0 = yy.x * (zz.x / (1.f + __expf(-zz.x)));
        float g1 = yy.y * (zz.y / (1.f + __expf(-zz.y)));
        g[j * 2 + 0] = g0;
        g[j * 2 + 1] = g1;
        ss += g0 * g0 + g1 * g1;
    }
#pragma unroll
    for (int m = 1; m < 64; m <<= 1) ss += __shfl_xor(ss, m);
    __shared__ float red[4];
    if ((tid & 63) == 0) red[tid >> 6] = ss;
    __syncthreads();
    float tot = red[0] + red[1] + red[2] + red[3];
    float scale = rsqrtf(tot * (1.f / DINNER) + 1e-5f);
#pragma unroll
    for (int j = 0; j < 3; ++j) {
        int idx = tid + j * 256;
        float2 w = nw2[idx];
        __hip_bfloat162 o;
        o.x = __float2bfloat16(g[j * 2 + 0] * scale * w.x);
        o.y = __float2bfloat16(g[j * 2 + 1] * scale * w.y);
        *(__hip_bfloat162*)(gbf + (size_t)row * DINNER + idx * 2) = o;
    }
}

// ---------------- launch ----------------
extern "C" void kernel_launch(void* const* d_in, const int* in_sizes, int n_in,
                              void* d_out, int out_size, void* d_ws, size_t ws_size,
                              hipStream_t stream)
{
    const float* u       = (const float*)d_in[0];
    const float* W_in    = (const float*)d_in[1];
    const float* conv_w  = (const float*)d_in[2];
    const float* conv_b  = (const float*)d_in[3];
    const float* dt_bias = (const float*)d_in[4];
    const float* A_log   = (const float*)d_in[5];
    const float* Dp      = (const float*)d_in[6];
    const float* norm_w  = (const float*)d_in[7];
    const float* W_out   = (const float*)d_in[8];
    float* out = (float*)d_out;

    char* ws = (char*)d_ws;
    size_t off = 0;
    auto alloc = [&](size_t bytes) {
        char* p = ws + off;
        off += (bytes + 255) & ~(size_t)255;
        return p;
    };
    __hip_bfloat16* ubf  = (__hip_bfloat16*)alloc((size_t)ROWS * DMODEL * 2);
    __hip_bfloat16* W1bf = (__hip_bfloat16*)alloc((size_t)NPAD1 * DMODEL * 2);
    __hip_bfloat16* W2bf = (__hip_bfloat16*)alloc((size_t)DMODEL * DINNER * 2);
    float* zbuf  = (float*)alloc((size_t)ROWS * DINNER * 4);   // z columns
    float* xbcdt = (float*)alloc((size_t)ROWS * DXBC * 4);     // xBC + dt columns
    float* xbuf = (float*)alloc((size_t)ROWS * DINNER * 4);
    float* Bmb  = (float*)alloc((size_t)ROWS * DSTATE * 4);
    float* Cmb  = (float*)alloc((size_t)ROWS * DSTATE * 4);
    float* dtb  = (float*)alloc((size_t)ROWS * NHEADS * 4);
    float* dAb  = (float*)alloc((size_t)ROWS * NHEADS * 4);
    float* ybuf = (float*)alloc((size_t)ROWS * DINNER * 4);
    float* Pkb  = (float*)alloc((size_t)BATCH * NHEADS * NCHUNK * 4);
    __hip_bfloat16* gbf = (__hip_bfloat16*)xbuf;  // reuse: xbuf dead after scan
    // ALIAS: xbcdt (54.9 MB) dead after conv+dt; Sloc (50.3 MB) reuses it.
    float* Sloc = (float*)xbcdt;
    bool chunked = (off <= ws_size);

    cvt_bf16_kernel<<<(ROWS * DMODEL / 4 + 255) / 256, 256, 0, stream>>>(u, ubf, ROWS * DMODEL);
    padw1_kernel<<<(NPAD1 * DMODEL + 255) / 256, 256, 0, stream>>>(W_in, W1bf);
    cvt_bf16_kernel<<<(DMODEL * DINNER / 4 + 255) / 256, 256, 0, stream>>>(W_out, W2bf, DMODEL * DINNER);

    // GEMM1: single pass, per-tile routed output (z | xBCdt)
    gemm1_fused<<<dim3(ROWS / 128, NPAD1 / 128), 256, 0, stream>>>(
        ubf, W1bf, zbuf, xbcdt);

    conv_kernel<<<dim3((CONVDIM + 255) / 256, ROWS / CROWS), 256, 0, stream>>>(
        xbcdt, conv_w, conv_b, xbuf, Bmb, Cmb);

    dt_kernel<<<(ROWS * NHEADS + 255) / 256, 256, 0, stream>>>(xbcdt, dt_bias, A_log, dtb, dAb);

    if (chunked) {
        chunk_state_f32<<<BATCH * NHEADS * NCHUNK, 256, 0, stream>>>(
            xbuf, Bmb, dtb, dAb, Sloc, Pkb);
        scan_phase2<<<BATCH * NHEADS * 32, 256, 0, stream>>>(Sloc, Pkb);
        chunk_y_f32<<<BATCH * NHEADS * NCHUNK / 2, 256, 0, stream>>>(
            xbuf, Bmb, Cmb, dtb, dAb, Dp, Sloc, ybuf);
    } else {
        scan_kernel<<<BATCH * NHEADS * 8, 256, 0, stream>>>(
            xbuf, Bmb, Cmb, dtb, dAb, Dp, ybuf);
    }

    gate_rms_kernel<<<ROWS, 256, 0, stream>>>(ybuf, zbuf, norm_w, gbf);

    gemm_bf16_nt<<<dim3(ROWS / 128, DMODEL / 128), 256, 0, stream>>>(
        gbf, W2bf, out, ROWS, DMODEL, DINNER, DMODEL);
}

// Round 16
// 296.125 us; speedup vs baseline: 1.0309x; 1.0309x over previous
//
#include <hip/hip_runtime.h>
#include <hip/hip_bf16.h>
#include <stdint.h>

#define BATCH   2
#define SEQLEN  4096
#define DMODEL  768
#define DSTATE  64
#define DCONV   4
#define HEADDIM 128
#define NHEADS  12
#define DINNER  1536
#define DINPROJ 3212
#define CONVDIM 1664
#define DXBC    1676            // CONVDIM + NHEADS (xBC + dt columns)
#define NPAD1   3328            // 26*128, padded rows of W_in (bf16 copy)
#define ROWS    (BATCH*SEQLEN)  // 8192
#define CHUNK   64
#define NCHUNK  (SEQLEN/CHUNK)  // 64
#define CROWS   8               // rows per conv block
#define TBUF    4096            // GEMM LDS buffer stride (elements) = 128*32

typedef __bf16 bf16x8 __attribute__((ext_vector_type(8)));
typedef float  f32x4  __attribute__((ext_vector_type(4)));

__device__ __forceinline__ f32x4 splat4(float v) { return (f32x4){v, v, v, v}; }

__device__ __forceinline__ void load_lds16(const void* g, void* l) {
    __builtin_amdgcn_global_load_lds(
        (const __attribute__((address_space(1))) unsigned int*)g,
        (__attribute__((address_space(3))) unsigned int*)l, 16, 0, 0);
}

// ---------------- conversion kernels ----------------
__global__ void cvt_bf16_kernel(const float* __restrict__ src,
                                __hip_bfloat16* __restrict__ dst, int n) {
    int i = (blockIdx.x * blockDim.x + threadIdx.x) * 4;
    if (i + 3 < n) {
        float4 v = *(const float4*)(src + i);
        dst[i + 0] = __float2bfloat16(v.x);
        dst[i + 1] = __float2bfloat16(v.y);
        dst[i + 2] = __float2bfloat16(v.z);
        dst[i + 3] = __float2bfloat16(v.w);
    } else {
        for (; i < n; ++i) dst[i] = __float2bfloat16(src[i]);
    }
}

__global__ void padw1_kernel(const float* __restrict__ src,
                             __hip_bfloat16* __restrict__ dst) {
    int i = blockIdx.x * blockDim.x + threadIdx.x;
    if (i >= NPAD1 * DMODEL) return;
    int r = i / DMODEL;
    float v = (r < DINPROJ) ? src[i] : 0.f;
    dst[i] = __float2bfloat16(v);
}

// ---------------- bf16 MFMA GEMM (double-buffered, swizzled LDS) ------------
__global__ __launch_bounds__(256) void gemm_bf16_nt(
    const __hip_bfloat16* __restrict__ A,
    const __hip_bfloat16* __restrict__ Bt,
    float* __restrict__ C,
    int M, int Nreal, int K, int ldc)
{
    __shared__ __align__(16) __hip_bfloat16 As[2 * TBUF];
    __shared__ __align__(16) __hip_bfloat16 Bs[2 * TBUF];
    const int tid  = threadIdx.x;
    const int lane = tid & 63;
    const int wave = tid >> 6;
    const int wm   = wave >> 1;
    const int wn   = wave & 1;
    const int tm   = blockIdx.x * 128;
    const int tn   = blockIdx.y * 128;

    f32x4 acc[4][4] = {};

    const int lrow = tid >> 2;
    const int lk8s = ((tid & 3) * 8) ^ (((tid >> 3) & 3) << 3);
    const __hip_bfloat16* gA0 = A  + (size_t)(tm + lrow)      * K + lk8s;
    const __hip_bfloat16* gA1 = A  + (size_t)(tm + lrow + 64) * K + lk8s;
    const __hip_bfloat16* gB0 = Bt + (size_t)(tn + lrow)      * K + lk8s;
    const __hip_bfloat16* gB1 = Bt + (size_t)(tn + lrow + 64) * K + lk8s;

    const int fr  = lane & 15;
    const int fks = ((lane >> 4) * 8) ^ (((lane >> 1) & 3) << 3);

    load_lds16(gA0, As + tid * 8);
    load_lds16(gA1, As + tid * 8 + 2048);
    load_lds16(gB0, Bs + tid * 8);
    load_lds16(gB1, Bs + tid * 8 + 2048);
    __syncthreads();

    int bufo = 0;
    for (int kk = 0; kk < K; kk += 32) {
        const int nbufo = bufo ^ TBUF;
        if (kk + 32 < K) {
            load_lds16(gA0 + kk + 32, As + nbufo + tid * 8);
            load_lds16(gA1 + kk + 32, As + nbufo + tid * 8 + 2048);
            load_lds16(gB0 + kk + 32, Bs + nbufo + tid * 8);
            load_lds16(gB1 + kk + 32, Bs + nbufo + tid * 8 + 2048);
        }
        bf16x8 af[4], bfr[4];
#pragma unroll
        for (int i = 0; i < 4; ++i) {
            af[i]  = *(const bf16x8*)(As + bufo + (wm * 64 + i * 16 + fr) * 32 + fks);
            bfr[i] = *(const bf16x8*)(Bs + bufo + (wn * 64 + i * 16 + fr) * 32 + fks);
        }
#pragma unroll
        for (int mi = 0; mi < 4; ++mi)
#pragma unroll
            for (int ni = 0; ni < 4; ++ni)
                acc[mi][ni] = __builtin_amdgcn_mfma_f32_16x16x32_bf16(
                    af[mi], bfr[ni], acc[mi][ni], 0, 0, 0);
        __syncthreads();
        bufo = nbufo;
    }

    const int rq = (lane >> 4) * 4;
#pragma unroll
    for (int mi = 0; mi < 4; ++mi) {
#pragma unroll
        for (int ni = 0; ni < 4; ++ni) {
            int col = tn + wn * 64 + ni * 16 + fr;
            if (col < Nreal) {
                size_t rbase = (size_t)(tm + wm * 64 + mi * 16 + rq) * ldc + col;
#pragma unroll
                for (int j = 0; j < 4; ++j)
                    C[rbase + (size_t)j * ldc] = acc[mi][ni][j];
            }
        }
    }
}

// ---------------- GEMM1 fused (double-buffered, swizzled, tile-routed) ------
__global__ __launch_bounds__(256) void gemm1_fused(
    const __hip_bfloat16* __restrict__ A,
    const __hip_bfloat16* __restrict__ Bt,
    float* __restrict__ Cz,     // (ROWS, DINNER)
    float* __restrict__ Cx)     // (ROWS, DXBC)
{
    __shared__ __align__(16) __hip_bfloat16 As[2 * TBUF];
    __shared__ __align__(16) __hip_bfloat16 Bs[2 * TBUF];
    const int tid  = threadIdx.x;
    const int lane = tid & 63;
    const int wave = tid >> 6;
    const int wm   = wave >> 1;
    const int wn   = wave & 1;
    const int tm   = blockIdx.x * 128;
    const int tn   = blockIdx.y * 128;
    const int K    = DMODEL;

    float* Co;
    int ldc2, cb, nb;
    if (tn < DINNER) { Co = Cz; ldc2 = DINNER; cb = tn;          nb = DINNER; }
    else             { Co = Cx; ldc2 = DXBC;   cb = tn - DINNER; nb = DXBC;   }

    f32x4 acc[4][4] = {};

    const int lrow = tid >> 2;
    const int lk8s = ((tid & 3) * 8) ^ (((tid >> 3) & 3) << 3);
    const __hip_bfloat16* gA0 = A  + (size_t)(tm + lrow)      * K + lk8s;
    const __hip_bfloat16* gA1 = A  + (size_t)(tm + lrow + 64) * K + lk8s;
    const __hip_bfloat16* gB0 = Bt + (size_t)(tn + lrow)      * K + lk8s;
    const __hip_bfloat16* gB1 = Bt + (size_t)(tn + lrow + 64) * K + lk8s;

    const int fr  = lane & 15;
    const int fks = ((lane >> 4) * 8) ^ (((lane >> 1) & 3) << 3);

    load_lds16(gA0, As + tid * 8);
    load_lds16(gA1, As + tid * 8 + 2048);
    load_lds16(gB0, Bs + tid * 8);
    load_lds16(gB1, Bs + tid * 8 + 2048);
    __syncthreads();

    int bufo = 0;
    for (int kk = 0; kk < K; kk += 32) {
        const int nbufo = bufo ^ TBUF;
        if (kk + 32 < K) {
            load_lds16(gA0 + kk + 32, As + nbufo + tid * 8);
            load_lds16(gA1 + kk + 32, As + nbufo + tid * 8 + 2048);
            load_lds16(gB0 + kk + 32, Bs + nbufo + tid * 8);
            load_lds16(gB1 + kk + 32, Bs + nbufo + tid * 8 + 2048);
        }
        bf16x8 af[4], bfr[4];
#pragma unroll
        for (int i = 0; i < 4; ++i) {
            af[i]  = *(const bf16x8*)(As + bufo + (wm * 64 + i * 16 + fr) * 32 + fks);
            bfr[i] = *(const bf16x8*)(Bs + bufo + (wn * 64 + i * 16 + fr) * 32 + fks);
        }
#pragma unroll
        for (int mi = 0; mi < 4; ++mi)
#pragma unroll
            for (int ni = 0; ni < 4; ++ni)
                acc[mi][ni] = __builtin_amdgcn_mfma_f32_16x16x32_bf16(
                    af[mi], bfr[ni], acc[mi][ni], 0, 0, 0);
        __syncthreads();
        bufo = nbufo;
    }

    const int rq = (lane >> 4) * 4;
#pragma unroll
    for (int mi = 0; mi < 4; ++mi) {
#pragma unroll
        for (int ni = 0; ni < 4; ++ni) {
            int col = cb + wn * 64 + ni * 16 + fr;
            if (col < nb) {
                size_t rbase = (size_t)(tm + wm * 64 + mi * 16 + rq) * ldc2 + col;
#pragma unroll
                for (int j = 0; j < 4; ++j)
                    Co[rbase + (size_t)j * ldc2] = acc[mi][ni][j];
            }
        }
    }
}

// ---------------- conv (8 rows/block, rolling window) + fused dt/dA ---------
// Threads with c in [CONVDIM, DXBC) compute softplus(dt)+dA instead of conv.
__global__ void conv_kernel(const float* __restrict__ xbcdt,
                            const float* __restrict__ convw,
                            const float* __restrict__ convb,
                            const float* __restrict__ dt_bias,
                            const float* __restrict__ A_log,
                            float* __restrict__ xbuf,
                            float* __restrict__ Bm,
                            float* __restrict__ Cm,
                            float* __restrict__ dtb,
                            float* __restrict__ dAb)
{
    int c = blockIdx.x * 256 + threadIdx.x;
    size_t row0 = (size_t)blockIdx.y * CROWS;
    if (c < CONVDIM) {
        int l0 = (int)(row0 & (SEQLEN - 1));
        float w0 = convw[c * 4 + 0];
        float w1 = convw[c * 4 + 1];
        float w2 = convw[c * 4 + 2];
        float w3 = convw[c * 4 + 3];
        float bias = convb[c];
        const float* src = xbcdt + row0 * DXBC + c;
        float x0 = (l0 >= 3) ? src[-3 * DXBC] : 0.f;
        float x1 = (l0 >= 2) ? src[-2 * DXBC] : 0.f;
        float x2 = (l0 >= 1) ? src[-1 * DXBC] : 0.f;
#pragma unroll
        for (int r = 0; r < CROWS; ++r) {
            float x3 = src[(size_t)r * DXBC];
            float acc = bias + x0 * w0 + x1 * w1 + x2 * w2 + x3 * w3;
            float v = acc / (1.f + __expf(-acc));
            size_t row = row0 + r;
            if (c < DINNER)               xbuf[row * DINNER + c] = v;
            else if (c < DINNER + DSTATE) Bm[row * DSTATE + (c - DINNER)] = v;
            else                          Cm[row * DSTATE + (c - DINNER - DSTATE)] = v;
            x0 = x1; x1 = x2; x2 = x3;
        }
    } else if (c < DXBC) {
        int h = c - CONVDIM;
        float bias = dt_bias[h];
        float A = -__expf(A_log[h]);
        const float* src = xbcdt + row0 * DXBC + c;
#pragma unroll
        for (int r = 0; r < CROWS; ++r) {
            float v = src[(size_t)r * DXBC] + bias;
            float dt = (v > 20.f) ? v : log1pf(__expf(v));
            size_t row = row0 + r;
            dtb[row * NHEADS + h] = dt;
            dAb[row * NHEADS + h] = __expf(dt * A);
        }
    }
}

// ======== chunk state kernel: thread owns 4p x 8n (256 thr, no reduce) ======
__global__ __launch_bounds__(256) void chunk_state_f32(
    const float* __restrict__ xbuf, const float* __restrict__ Bm,
    const float* __restrict__ dtb, const float* __restrict__ dAb,
    float* __restrict__ Sloc, float* __restrict__ Pk)
{
    const int blk = blockIdx.x;
    const int k   = blk % NCHUNK;
    const int bh  = blk / NCHUNK;
    const int h   = bh % NHEADS;
    const int b   = bh / NHEADS;
    const int tid = threadIdx.x;
    const int pg  = tid >> 3;
    const int n0  = (tid & 7) * 8;
    const size_t row0 = (size_t)b * SEQLEN + k * CHUNK;
    const float* xbase = xbuf + (row0 * NHEADS + h) * HEADDIM + pg * 4;

    __shared__ __align__(16) float lB[CHUNK][DSTATE];    // 16 KB
    __shared__ float lDA[CHUNK];
    __shared__ float ldt[CHUNK];

    for (int i = tid; i < CHUNK * DSTATE / 4; i += 256)
        ((float4*)&lB[0][0])[i] = ((const float4*)(Bm + row0 * DSTATE))[i];
    if (tid < CHUNK) {
        lDA[tid] = dAb[(row0 + tid) * NHEADS + h];
        ldt[tid] = dtb[(row0 + tid) * NHEADS + h];
    }
    __syncthreads();

    f32x4 s4[4][2] = {};
    f32x4 xt0[4], xt1[4];

#pragma unroll
    for (int tt = 0; tt < 4; ++tt)
        xt0[tt] = *(const f32x4*)(xbase + (size_t)tt * (NHEADS * HEADDIM));

#pragma unroll
    for (int tile = 0; tile < 16; ++tile) {
        f32x4* cur = (tile & 1) ? xt1 : xt0;
        f32x4* nxt = (tile & 1) ? xt0 : xt1;
        if (tile < 15) {
#pragma unroll
            for (int tt = 0; tt < 4; ++tt)
                nxt[tt] = *(const f32x4*)(xbase +
                    (size_t)((tile + 1) * 4 + tt) * (NHEADS * HEADDIM));
        }
#pragma unroll
        for (int tt = 0; tt < 4; ++tt) {
            int t = tile * 4 + tt;
            f32x4 da4 = splat4(lDA[t]);
            float dtv = ldt[t];
            f32x4 bv0 = *(const f32x4*)&lB[t][n0];
            f32x4 bv1 = *(const f32x4*)&lB[t][n0 + 4];
#pragma unroll
            for (int pl = 0; pl < 4; ++pl) {
                f32x4 dtx = splat4(dtv * cur[tt][pl]);
                s4[pl][0] = s4[pl][0] * da4 + dtx * bv0;
                s4[pl][1] = s4[pl][1] * da4 + dtx * bv1;
            }
        }
    }

    const size_t kbase = (size_t)(bh * NCHUNK + k) * (HEADDIM * DSTATE);
#pragma unroll
    for (int pl = 0; pl < 4; ++pl) {
        size_t a = kbase + (size_t)(pg * 4 + pl) * DSTATE + n0;
        *(f32x4*)(Sloc + a)     = s4[pl][0];
        *(f32x4*)(Sloc + a + 4) = s4[pl][1];
    }

    if (tid == 0) {
        float pr = 1.f;
#pragma unroll 8
        for (int t = 0; t < CHUNK; ++t) pr *= lDA[t];
        Pk[bh * NCHUNK + k] = pr;
    }
}

// ---------------- scan phase 2: inter-chunk prefix (in-place F -> S_init) --
__global__ __launch_bounds__(256) void scan_phase2(
    float* __restrict__ Sloc, const float* __restrict__ Pk)
{
    int bh = blockIdx.x >> 5;
    int eo = (blockIdx.x & 31) * 256 + threadIdx.x;
    __shared__ float lP[NCHUNK];
    if (threadIdx.x < NCHUNK) lP[threadIdx.x] = Pk[bh * NCHUNK + threadIdx.x];
    __syncthreads();
    float s = 0.f;
    size_t base = (size_t)bh * NCHUNK * 8192 + eo;
#pragma unroll 8
    for (int k = 0; k < NCHUNK; ++k) {
        size_t a = base + (size_t)k * 8192;
        float f = Sloc[a];
        Sloc[a] = s;
        s = s * lP[k] + f;
    }
}

// ======== chunk y kernel: thread owns 2p x 16n (R10/R11 verified config) ====
// pg = tid>>2, q = tid&3, n0 = q*16; y reduced over quad via xor1+xor2 (DPP).
// VGPR 64 -> ~31% occupancy; this config measured 78 us.
__global__ __launch_bounds__(256) void chunk_y_f32(
    const float* __restrict__ xbuf, const float* __restrict__ Bm,
    const float* __restrict__ Cm, const float* __restrict__ dtb,
    const float* __restrict__ dAb, const float* __restrict__ Dp,
    const float* __restrict__ Sini, float* __restrict__ ybuf)
{
    const int blk = blockIdx.x;
    const int k   = blk % NCHUNK;
    const int bh  = blk / NCHUNK;
    const int h   = bh % NHEADS;
    const int b   = bh / NHEADS;
    const int tid = threadIdx.x;
    const int pg  = tid >> 2;
    const int q   = tid & 3;
    const int n0  = q * 16;
    const size_t row0 = (size_t)b * SEQLEN + k * CHUNK;
    const float* xbase = xbuf + (row0 * NHEADS + h) * HEADDIM + pg * 2;
    float* ybase = ybuf + (row0 * NHEADS + h) * HEADDIM + pg * 2;

    __shared__ __align__(16) float lB[CHUNK][DSTATE];    // 16 KB
    __shared__ __align__(16) float lC[CHUNK][DSTATE];    // 16 KB
    __shared__ float lDA[CHUNK];
    __shared__ float ldt[CHUNK];

    for (int i = tid; i < CHUNK * DSTATE / 4; i += 256) {
        ((float4*)&lB[0][0])[i] = ((const float4*)(Bm + row0 * DSTATE))[i];
        ((float4*)&lC[0][0])[i] = ((const float4*)(Cm + row0 * DSTATE))[i];
    }
    if (tid < CHUNK) {
        lDA[tid] = dAb[(row0 + tid) * NHEADS + h];
        ldt[tid] = dtb[(row0 + tid) * NHEADS + h];
    }

    // seed 2p x 16n states from S_init (f32)
    f32x4 s4[2][4];
    const size_t kbase = (size_t)(bh * NCHUNK + k) * (HEADDIM * DSTATE);
#pragma unroll
    for (int pl = 0; pl < 2; ++pl) {
        size_t a = kbase + (size_t)(pg * 2 + pl) * DSTATE + n0;
#pragma unroll
        for (int nq = 0; nq < 4; ++nq)
            s4[pl][nq] = *(const f32x4*)(Sini + a + nq * 4);
    }
    const float dph = Dp[h];

    float xa[2][8], xb[2][8];
#pragma unroll
    for (int tt = 0; tt < 8; ++tt) {
        float2 v = *(const float2*)(xbase + (size_t)tt * (NHEADS * HEADDIM));
        xa[0][tt] = v.x; xa[1][tt] = v.y;
    }
    __syncthreads();

#pragma unroll
    for (int tile = 0; tile < 8; ++tile) {
        float (*cur)[8] = (tile & 1) ? xb : xa;
        float (*nxt)[8] = (tile & 1) ? xa : xb;
        if (tile < 7) {
#pragma unroll
            for (int tt = 0; tt < 8; ++tt) {
                float2 v = *(const float2*)(xbase +
                    (size_t)((tile + 1) * 8 + tt) * (NHEADS * HEADDIM));
                nxt[0][tt] = v.x; nxt[1][tt] = v.y;
            }
        }
#pragma unroll
        for (int tt = 0; tt < 8; ++tt) {
            int t = tile * 8 + tt;
            f32x4 da4 = splat4(lDA[t]);
            float dtv = ldt[t];
            f32x4 bv0 = *(const f32x4*)&lB[t][n0];
            f32x4 bv1 = *(const f32x4*)&lB[t][n0 + 4];
            f32x4 bv2 = *(const f32x4*)&lB[t][n0 + 8];
            f32x4 bv3 = *(const f32x4*)&lB[t][n0 + 12];
            f32x4 cv0 = *(const f32x4*)&lC[t][n0];
            f32x4 cv1 = *(const f32x4*)&lC[t][n0 + 4];
            f32x4 cv2 = *(const f32x4*)&lC[t][n0 + 8];
            f32x4 cv3 = *(const f32x4*)&lC[t][n0 + 12];
            float yr[2];
#pragma unroll
            for (int pl = 0; pl < 2; ++pl) {
                f32x4 dtx = splat4(dtv * cur[pl][tt]);
                f32x4 v0 = s4[pl][0] * da4 + dtx * bv0;
                f32x4 v1 = s4[pl][1] * da4 + dtx * bv1;
                f32x4 v2 = s4[pl][2] * da4 + dtx * bv2;
                f32x4 v3 = s4[pl][3] * da4 + dtx * bv3;
                s4[pl][0] = v0; s4[pl][1] = v1; s4[pl][2] = v2; s4[pl][3] = v3;
                f32x4 y4 = cv0 * v0 + cv1 * v1 + cv2 * v2 + cv3 * v3;
                float y = (y4[0] + y4[1]) + (y4[2] + y4[3]);
                y += __shfl_xor(y, 1);   // quad_perm DPP
                y += __shfl_xor(y, 2);   // quad_perm DPP
                yr[pl] = y;
            }
            if (q == 0) {
                float2 w = {yr[0] + dph * cur[0][tt], yr[1] + dph * cur[1][tt]};
                *(float2*)(ybase + (size_t)t * (NHEADS * HEADDIM)) = w;
            }
        }
    }
}

// ---------------- fallback: original monolithic scan ------------------------
#define NT 64
__global__ __launch_bounds__(256) void scan_kernel(
    const float* __restrict__ xbuf, const float* __restrict__ Bm,
    const float* __restrict__ Cm, const float* __restrict__ dtb,
    const float* __restrict__ dAb, const float* __restrict__ Dp,
    float* __restrict__ ybuf)
{
    int blk = blockIdx.x;
    int ps = blk & 7;
    int h  = (blk >> 3) % NHEADS;
    int b  = blk / (NHEADS * 8);
    int p0 = ps * 16;
    int tid = threadIdx.x;
    int pl  = tid >> 4;
    int n0  = (tid & 15) * 4;

    __shared__ __align__(16) float lB[NT][64];
    __shared__ __align__(16) float lC[NT][64];
    __shared__ __align__(16) float lDtx[NT][16];
    __shared__ float lDA[NT];
    __shared__ float lY[NT][16];

    float s0 = 0.f, s1 = 0.f, s2 = 0.f, s3 = 0.f;
    float dph = Dp[h];
    size_t rowbase = (size_t)b * SEQLEN;

    for (int t0 = 0; t0 < SEQLEN; t0 += NT) {
        for (int i = tid; i < NT * 64 / 4; i += 256) {
            ((float4*)&lB[0][0])[i] = ((const float4*)Bm)[(rowbase + t0) * 16 + i];
            ((float4*)&lC[0][0])[i] = ((const float4*)Cm)[(rowbase + t0) * 16 + i];
        }
        for (int i = tid; i < NT * 16; i += 256) {
            int t = i >> 4, pp = i & 15;
            size_t r = rowbase + t0 + t;
            lDtx[t][pp] = dtb[r * NHEADS + h] * xbuf[(r * NHEADS + h) * HEADDIM + p0 + pp];
        }
        if (tid < NT) lDA[tid] = dAb[(rowbase + t0 + tid) * NHEADS + h];
        __syncthreads();

        for (int t = 0; t < NT; ++t) {
            float da  = lDA[t];
            float dtx = lDtx[t][pl];
            const float* bp = &lB[t][n0];
            const float* cp = &lC[t][n0];
            s0 = s0 * da + dtx * bp[0];
            s1 = s1 * da + dtx * bp[1];
            s2 = s2 * da + dtx * bp[2];
            s3 = s3 * da + dtx * bp[3];
            float part = s0 * cp[0] + s1 * cp[1] + s2 * cp[2] + s3 * cp[3];
            part += __shfl_xor(part, 1);
            part += __shfl_xor(part, 2);
            part += __shfl_xor(part, 4);
            part += __shfl_xor(part, 8);
            if ((tid & 15) == 0) lY[t][pl] = part;
        }
        __syncthreads();

        for (int i = tid; i < NT * 16; i += 256) {
            int t = i >> 4, pp = i & 15;
            size_t r = rowbase + t0 + t;
            size_t gi = (r * NHEADS + h) * HEADDIM + p0 + pp;
            ybuf[gi] = lY[t][pp] + dph * xbuf[gi];
        }
        __syncthreads();
    }
}

// ---------------- gate (y * silu(z)) + RMSNorm -> bf16 (float2 path) --------
__global__ __launch_bounds__(256) void gate_rms_kernel(
    const float* __restrict__ ybuf, const float* __restrict__ zbuf,
    const float* __restrict__ norm_w, __hip_bfloat16* __restrict__ gbf)
{
    int row = blockIdx.x;
    int tid = threadIdx.x;
    const float2* y2 = (const float2*)(ybuf + (size_t)row * DINNER);
    const float2* z2 = (const float2*)(zbuf + (size_t)row * DINNER);
    const float2* nw2 = (const float2*)norm_w;
    float g[6];
    float ss = 0.f;
#pragma unroll
    for (int j = 0; j < 3; ++j) {
        int idx = tid + j * 256;
        float2 yy = y2[idx];
        float2 zz = z2[idx];
        float g0 = yy.x * (zz.x / (1.f + __expf(-zz.x)));
        float g1 = yy.y * (zz.y / (1.f + __expf(-zz.y)));
        g[j * 2 + 0] = g0;
        g[j * 2 + 1] = g1;
        ss += g0 * g0 + g1 * g1;
    }
#pragma unroll
    for (int m = 1; m < 64; m <<= 1) ss += __shfl_xor(ss, m);
    __shared__ float red[4];
    if ((tid & 63) == 0) red[tid >> 6] = ss;
    __syncthreads();
    float tot = red[0] + red[1] + red[2] + red[3];
    float scale = rsqrtf(tot * (1.f / DINNER) + 1e-5f);
#pragma unroll
    for (int j = 0; j < 3; ++j) {
        int idx = tid + j * 256;
        float2 w = nw2[idx];
        __hip_bfloat162 o;
        o.x = __float2bfloat16(g[j * 2 + 0] * scale * w.x);
        o.y = __float2bfloat16(g[j * 2 + 1] * scale * w.y);
        *(__hip_bfloat162*)(gbf + (size_t)row * DINNER + idx * 2) = o;
    }
}

// ---------------- launch ----------------
extern "C" void kernel_launch(void* const* d_in, const int* in_sizes, int n_in,
                              void* d_out, int out_size, void* d_ws, size_t ws_size,
                              hipStream_t stream)
{
    const float* u       = (const float*)d_in[0];
    const float* W_in    = (const float*)d_in[1];
    const float* conv_w  = (const float*)d_in[2];
    const float* conv_b  = (const float*)d_in[3];
    const float* dt_bias = (const float*)d_in[4];
    const float* A_log   = (const float*)d_in[5];
    const float* Dp      = (const float*)d_in[6];
    const float* norm_w  = (const float*)d_in[7];
    const float* W_out   = (const float*)d_in[8];
    float* out = (float*)d_out;

    char* ws = (char*)d_ws;
    size_t off = 0;
    auto alloc = [&](size_t bytes) {
        char* p = ws + off;
        off += (bytes + 255) & ~(size_t)255;
        return p;
    };
    __hip_bfloat16* ubf  = (__hip_bfloat16*)alloc((size_t)ROWS * DMODEL * 2);
    __hip_bfloat16* W1bf = (__hip_bfloat16*)alloc((size_t)NPAD1 * DMODEL * 2);
    __hip_bfloat16* W2bf = (__hip_bfloat16*)alloc((size_t)DMODEL * DINNER * 2);
    float* zbuf  = (float*)alloc((size_t)ROWS * DINNER * 4);   // z columns
    float* xbcdt = (float*)alloc((size_t)ROWS * DXBC * 4);     // xBC + dt columns
    float* xbuf = (float*)alloc((size_t)ROWS * DINNER * 4);
    float* Bmb  = (float*)alloc((size_t)ROWS * DSTATE * 4);
    float* Cmb  = (float*)alloc((size_t)ROWS * DSTATE * 4);
    float* dtb  = (float*)alloc((size_t)ROWS * NHEADS * 4);
    float* dAb  = (float*)alloc((size_t)ROWS * NHEADS * 4);
    float* ybuf = (float*)alloc((size_t)ROWS * DINNER * 4);
    float* Pkb  = (float*)alloc((size_t)BATCH * NHEADS * NCHUNK * 4);
    __hip_bfloat16* gbf = (__hip_bfloat16*)xbuf;  // reuse: xbuf dead after scan
    // ALIAS: xbcdt (54.9 MB) dead after conv+dt; Sloc (50.3 MB) reuses it.
    float* Sloc = (float*)xbcdt;
    bool chunked = (off <= ws_size);

    cvt_bf16_kernel<<<(ROWS * DMODEL / 4 + 255) / 256, 256, 0, stream>>>(u, ubf, ROWS * DMODEL);
    padw1_kernel<<<(NPAD1 * DMODEL + 255) / 256, 256, 0, stream>>>(W_in, W1bf);
    cvt_bf16_kernel<<<(DMODEL * DINNER / 4 + 255) / 256, 256, 0, stream>>>(W_out, W2bf, DMODEL * DINNER);

    // GEMM1: single pass, per-tile routed output (z | xBCdt)
    gemm1_fused<<<dim3(ROWS / 128, NPAD1 / 128), 256, 0, stream>>>(
        ubf, W1bf, zbuf, xbcdt);

    // conv + fused dt/dA (dt columns handled by the tail threads)
    conv_kernel<<<dim3((DXBC + 255) / 256, ROWS / CROWS), 256, 0, stream>>>(
        xbcdt, conv_w, conv_b, dt_bias, A_log, xbuf, Bmb, Cmb, dtb, dAb);

    if (chunked) {
        chunk_state_f32<<<BATCH * NHEADS * NCHUNK, 256, 0, stream>>>(
            xbuf, Bmb, dtb, dAb, Sloc, Pkb);
        scan_phase2<<<BATCH * NHEADS * 32, 256, 0, stream>>>(Sloc, Pkb);
        chunk_y_f32<<<BATCH * NHEADS * NCHUNK, 256, 0, stream>>>(
            xbuf, Bmb, Cmb, dtb, dAb, Dp, Sloc, ybuf);
    } else {
        scan_kernel<<<BATCH * NHEADS * 8, 256, 0, stream>>>(
            xbuf, Bmb, Cmb, dtb, dAb, Dp, ybuf);
    }

    gate_rms_kernel<<<ROWS, 256, 0, stream>>>(ybuf, zbuf, norm_w, gbf);

    gemm_bf16_nt<<<dim3(ROWS / 128, DMODEL / 128), 256, 0, stream>>>(
        gbf, W2bf, out, ROWS, DMODEL, DINNER, DMODEL);
}

// Round 17
// 278.932 us; speedup vs baseline: 1.0944x; 1.0616x over previous
//
#include <hip/hip_runtime.h>
#include <hip/hip_bf16.h>
#include <stdint.h>

#define BATCH   2
#define SEQLEN  4096
#define DMODEL  768
#define DSTATE  64
#define DCONV   4
#define HEADDIM 128
#define NHEADS  12
#define DINNER  1536
#define DINPROJ 3212
#define CONVDIM 1664
#define DXBC    1676            // CONVDIM + NHEADS (xBC + dt columns)
#define NPAD1   3328            // 26*128, padded rows of W_in (bf16 copy)
#define ROWS    (BATCH*SEQLEN)  // 8192
#define CHUNK   64
#define NCHUNK  (SEQLEN/CHUNK)  // 64
#define CROWS   8               // rows per conv block
#define TBUF    4096            // GEMM LDS buffer stride (elements) = 128*32

typedef __bf16 bf16x8 __attribute__((ext_vector_type(8)));
typedef float  f32x4  __attribute__((ext_vector_type(4)));
typedef unsigned short u16x8 __attribute__((ext_vector_type(8)));

__device__ __forceinline__ f32x4 splat4(float v) { return (f32x4){v, v, v, v}; }

__device__ __forceinline__ unsigned short f2bf(float f) {
    __hip_bfloat16 h = __float2bfloat16(f);
    return *reinterpret_cast<unsigned short*>(&h);
}
__device__ __forceinline__ float bf2f(unsigned short u) {
    return __uint_as_float(((unsigned int)u) << 16);
}

__device__ __forceinline__ void load_lds16(const void* g, void* l) {
    __builtin_amdgcn_global_load_lds(
        (const __attribute__((address_space(1))) unsigned int*)g,
        (__attribute__((address_space(3))) unsigned int*)l, 16, 0, 0);
}

// ---------------- fused prep: cvt u, pad+cvt W_in, cvt W_out ----------------
#define NPREP1 (ROWS*DMODEL)
#define NPREP2 (NPAD1*DMODEL)
#define NPREP3 (DMODEL*DINNER)
__global__ void prep_kernel(const float* __restrict__ u,
                            const float* __restrict__ W_in,
                            const float* __restrict__ W_out,
                            __hip_bfloat16* __restrict__ ubf,
                            __hip_bfloat16* __restrict__ W1bf,
                            __hip_bfloat16* __restrict__ W2bf)
{
    int i = (blockIdx.x * 256 + threadIdx.x) * 4;
    if (i < NPREP1) {
        float4 v = *(const float4*)(u + i);
        ubf[i + 0] = __float2bfloat16(v.x);
        ubf[i + 1] = __float2bfloat16(v.y);
        ubf[i + 2] = __float2bfloat16(v.z);
        ubf[i + 3] = __float2bfloat16(v.w);
    } else if (i < NPREP1 + NPREP2) {
        int j = i - NPREP1;
        int r = j / DMODEL;                 // 4-elem group never crosses rows
        if (r < DINPROJ) {
            float4 v = *(const float4*)(W_in + j);
            W1bf[j + 0] = __float2bfloat16(v.x);
            W1bf[j + 1] = __float2bfloat16(v.y);
            W1bf[j + 2] = __float2bfloat16(v.z);
            W1bf[j + 3] = __float2bfloat16(v.w);
        } else {
            __hip_bfloat16 z = __float2bfloat16(0.f);
            W1bf[j + 0] = z; W1bf[j + 1] = z; W1bf[j + 2] = z; W1bf[j + 3] = z;
        }
    } else if (i < NPREP1 + NPREP2 + NPREP3) {
        int j = i - NPREP1 - NPREP2;
        float4 v = *(const float4*)(W_out + j);
        W2bf[j + 0] = __float2bfloat16(v.x);
        W2bf[j + 1] = __float2bfloat16(v.y);
        W2bf[j + 2] = __float2bfloat16(v.z);
        W2bf[j + 3] = __float2bfloat16(v.w);
    }
}

// ---------------- bf16 MFMA GEMM (double-buffered, swizzled LDS) ------------
__global__ __launch_bounds__(256) void gemm_bf16_nt(
    const __hip_bfloat16* __restrict__ A,
    const __hip_bfloat16* __restrict__ Bt,
    float* __restrict__ C,
    int M, int Nreal, int K, int ldc)
{
    __shared__ __align__(16) __hip_bfloat16 As[2 * TBUF];
    __shared__ __align__(16) __hip_bfloat16 Bs[2 * TBUF];
    const int tid  = threadIdx.x;
    const int lane = tid & 63;
    const int wave = tid >> 6;
    const int wm   = wave >> 1;
    const int wn   = wave & 1;
    const int tm   = blockIdx.x * 128;
    const int tn   = blockIdx.y * 128;

    f32x4 acc[4][4] = {};

    const int lrow = tid >> 2;
    const int lk8s = ((tid & 3) * 8) ^ (((tid >> 3) & 3) << 3);
    const __hip_bfloat16* gA0 = A  + (size_t)(tm + lrow)      * K + lk8s;
    const __hip_bfloat16* gA1 = A  + (size_t)(tm + lrow + 64) * K + lk8s;
    const __hip_bfloat16* gB0 = Bt + (size_t)(tn + lrow)      * K + lk8s;
    const __hip_bfloat16* gB1 = Bt + (size_t)(tn + lrow + 64) * K + lk8s;

    const int fr  = lane & 15;
    const int fks = ((lane >> 4) * 8) ^ (((lane >> 1) & 3) << 3);

    load_lds16(gA0, As + tid * 8);
    load_lds16(gA1, As + tid * 8 + 2048);
    load_lds16(gB0, Bs + tid * 8);
    load_lds16(gB1, Bs + tid * 8 + 2048);
    __syncthreads();

    int bufo = 0;
    for (int kk = 0; kk < K; kk += 32) {
        const int nbufo = bufo ^ TBUF;
        if (kk + 32 < K) {
            load_lds16(gA0 + kk + 32, As + nbufo + tid * 8);
            load_lds16(gA1 + kk + 32, As + nbufo + tid * 8 + 2048);
            load_lds16(gB0 + kk + 32, Bs + nbufo + tid * 8);
            load_lds16(gB1 + kk + 32, Bs + nbufo + tid * 8 + 2048);
        }
        bf16x8 af[4], bfr[4];
#pragma unroll
        for (int i = 0; i < 4; ++i) {
            af[i]  = *(const bf16x8*)(As + bufo + (wm * 64 + i * 16 + fr) * 32 + fks);
            bfr[i] = *(const bf16x8*)(Bs + bufo + (wn * 64 + i * 16 + fr) * 32 + fks);
        }
#pragma unroll
        for (int mi = 0; mi < 4; ++mi)
#pragma unroll
            for (int ni = 0; ni < 4; ++ni)
                acc[mi][ni] = __builtin_amdgcn_mfma_f32_16x16x32_bf16(
                    af[mi], bfr[ni], acc[mi][ni], 0, 0, 0);
        __syncthreads();
        bufo = nbufo;
    }

    const int rq = (lane >> 4) * 4;
#pragma unroll
    for (int mi = 0; mi < 4; ++mi) {
#pragma unroll
        for (int ni = 0; ni < 4; ++ni) {
            int col = tn + wn * 64 + ni * 16 + fr;
            if (col < Nreal) {
                size_t rbase = (size_t)(tm + wm * 64 + mi * 16 + rq) * ldc + col;
#pragma unroll
                for (int j = 0; j < 4; ++j)
                    C[rbase + (size_t)j * ldc] = acc[mi][ni][j];
            }
        }
    }
}

// ---------------- GEMM1 fused (double-buffered, swizzled, tile-routed) ------
__global__ __launch_bounds__(256) void gemm1_fused(
    const __hip_bfloat16* __restrict__ A,
    const __hip_bfloat16* __restrict__ Bt,
    float* __restrict__ Cz,     // (ROWS, DINNER)
    float* __restrict__ Cx)     // (ROWS, DXBC)
{
    __shared__ __align__(16) __hip_bfloat16 As[2 * TBUF];
    __shared__ __align__(16) __hip_bfloat16 Bs[2 * TBUF];
    const int tid  = threadIdx.x;
    const int lane = tid & 63;
    const int wave = tid >> 6;
    const int wm   = wave >> 1;
    const int wn   = wave & 1;
    const int tm   = blockIdx.x * 128;
    const int tn   = blockIdx.y * 128;
    const int K    = DMODEL;

    float* Co;
    int ldc2, cb, nb;
    if (tn < DINNER) { Co = Cz; ldc2 = DINNER; cb = tn;          nb = DINNER; }
    else             { Co = Cx; ldc2 = DXBC;   cb = tn - DINNER; nb = DXBC;   }

    f32x4 acc[4][4] = {};

    const int lrow = tid >> 2;
    const int lk8s = ((tid & 3) * 8) ^ (((tid >> 3) & 3) << 3);
    const __hip_bfloat16* gA0 = A  + (size_t)(tm + lrow)      * K + lk8s;
    const __hip_bfloat16* gA1 = A  + (size_t)(tm + lrow + 64) * K + lk8s;
    const __hip_bfloat16* gB0 = Bt + (size_t)(tn + lrow)      * K + lk8s;
    const __hip_bfloat16* gB1 = Bt + (size_t)(tn + lrow + 64) * K + lk8s;

    const int fr  = lane & 15;
    const int fks = ((lane >> 4) * 8) ^ (((lane >> 1) & 3) << 3);

    load_lds16(gA0, As + tid * 8);
    load_lds16(gA1, As + tid * 8 + 2048);
    load_lds16(gB0, Bs + tid * 8);
    load_lds16(gB1, Bs + tid * 8 + 2048);
    __syncthreads();

    int bufo = 0;
    for (int kk = 0; kk < K; kk += 32) {
        const int nbufo = bufo ^ TBUF;
        if (kk + 32 < K) {
            load_lds16(gA0 + kk + 32, As + nbufo + tid * 8);
            load_lds16(gA1 + kk + 32, As + nbufo + tid * 8 + 2048);
            load_lds16(gB0 + kk + 32, Bs + nbufo + tid * 8);
            load_lds16(gB1 + kk + 32, Bs + nbufo + tid * 8 + 2048);
        }
        bf16x8 af[4], bfr[4];
#pragma unroll
        for (int i = 0; i < 4; ++i) {
            af[i]  = *(const bf16x8*)(As + bufo + (wm * 64 + i * 16 + fr) * 32 + fks);
            bfr[i] = *(const bf16x8*)(Bs + bufo + (wn * 64 + i * 16 + fr) * 32 + fks);
        }
#pragma unroll
        for (int mi = 0; mi < 4; ++mi)
#pragma unroll
            for (int ni = 0; ni < 4; ++ni)
                acc[mi][ni] = __builtin_amdgcn_mfma_f32_16x16x32_bf16(
                    af[mi], bfr[ni], acc[mi][ni], 0, 0, 0);
        __syncthreads();
        bufo = nbufo;
    }

    const int rq = (lane >> 4) * 4;
#pragma unroll
    for (int mi = 0; mi < 4; ++mi) {
#pragma unroll
        for (int ni = 0; ni < 4; ++ni) {
            int col = cb + wn * 64 + ni * 16 + fr;
            if (col < nb) {
                size_t rbase = (size_t)(tm + wm * 64 + mi * 16 + rq) * ldc2 + col;
#pragma unroll
                for (int j = 0; j < 4; ++j)
                    Co[rbase + (size_t)j * ldc2] = acc[mi][ni][j];
            }
        }
    }
}

// ---------------- conv (8 rows/block, rolling window) + fused dt/dA ---------
__global__ void conv_kernel(const float* __restrict__ xbcdt,
                            const float* __restrict__ convw,
                            const float* __restrict__ convb,
                            const float* __restrict__ dt_bias,
                            const float* __restrict__ A_log,
                            float* __restrict__ xbuf,
                            float* __restrict__ Bm,
                            float* __restrict__ Cm,
                            float* __restrict__ dtb,
                            float* __restrict__ dAb)
{
    int c = blockIdx.x * 256 + threadIdx.x;
    size_t row0 = (size_t)blockIdx.y * CROWS;
    if (c < CONVDIM) {
        int l0 = (int)(row0 & (SEQLEN - 1));
        float w0 = convw[c * 4 + 0];
        float w1 = convw[c * 4 + 1];
        float w2 = convw[c * 4 + 2];
        float w3 = convw[c * 4 + 3];
        float bias = convb[c];
        const float* src = xbcdt + row0 * DXBC + c;
        float x0 = (l0 >= 3) ? src[-3 * DXBC] : 0.f;
        float x1 = (l0 >= 2) ? src[-2 * DXBC] : 0.f;
        float x2 = (l0 >= 1) ? src[-1 * DXBC] : 0.f;
#pragma unroll
        for (int r = 0; r < CROWS; ++r) {
            float x3 = src[(size_t)r * DXBC];
            float acc = bias + x0 * w0 + x1 * w1 + x2 * w2 + x3 * w3;
            float v = acc / (1.f + __expf(-acc));
            size_t row = row0 + r;
            if (c < DINNER)               xbuf[row * DINNER + c] = v;
            else if (c < DINNER + DSTATE) Bm[row * DSTATE + (c - DINNER)] = v;
            else                          Cm[row * DSTATE + (c - DINNER - DSTATE)] = v;
            x0 = x1; x1 = x2; x2 = x3;
        }
    } else if (c < DXBC) {
        int h = c - CONVDIM;
        float bias = dt_bias[h];
        float A = -__expf(A_log[h]);
        const float* src = xbcdt + row0 * DXBC + c;
#pragma unroll
        for (int r = 0; r < CROWS; ++r) {
            float v = src[(size_t)r * DXBC] + bias;
            float dt = (v > 20.f) ? v : log1pf(__expf(v));
            size_t row = row0 + r;
            dtb[row * NHEADS + h] = dt;
            dAb[row * NHEADS + h] = __expf(dt * A);
        }
    }
}

// ======== chunk state kernel: 4p x 8n, bf16 state store =====================
__global__ __launch_bounds__(256) void chunk_state_f32(
    const float* __restrict__ xbuf, const float* __restrict__ Bm,
    const float* __restrict__ dtb, const float* __restrict__ dAb,
    unsigned short* __restrict__ Sloc, float* __restrict__ Pk)
{
    const int blk = blockIdx.x;
    const int k   = blk % NCHUNK;
    const int bh  = blk / NCHUNK;
    const int h   = bh % NHEADS;
    const int b   = bh / NHEADS;
    const int tid = threadIdx.x;
    const int pg  = tid >> 3;
    const int n0  = (tid & 7) * 8;
    const size_t row0 = (size_t)b * SEQLEN + k * CHUNK;
    const float* xbase = xbuf + (row0 * NHEADS + h) * HEADDIM + pg * 4;

    __shared__ __align__(16) float lB[CHUNK][DSTATE];    // 16 KB
    __shared__ float lDA[CHUNK];
    __shared__ float ldt[CHUNK];

    for (int i = tid; i < CHUNK * DSTATE / 4; i += 256)
        ((float4*)&lB[0][0])[i] = ((const float4*)(Bm + row0 * DSTATE))[i];
    if (tid < CHUNK) {
        lDA[tid] = dAb[(row0 + tid) * NHEADS + h];
        ldt[tid] = dtb[(row0 + tid) * NHEADS + h];
    }
    __syncthreads();

    f32x4 s4[4][2] = {};
    f32x4 xt0[4], xt1[4];

#pragma unroll
    for (int tt = 0; tt < 4; ++tt)
        xt0[tt] = *(const f32x4*)(xbase + (size_t)tt * (NHEADS * HEADDIM));

#pragma unroll
    for (int tile = 0; tile < 16; ++tile) {
        f32x4* cur = (tile & 1) ? xt1 : xt0;
        f32x4* nxt = (tile & 1) ? xt0 : xt1;
        if (tile < 15) {
#pragma unroll
            for (int tt = 0; tt < 4; ++tt)
                nxt[tt] = *(const f32x4*)(xbase +
                    (size_t)((tile + 1) * 4 + tt) * (NHEADS * HEADDIM));
        }
#pragma unroll
        for (int tt = 0; tt < 4; ++tt) {
            int t = tile * 4 + tt;
            f32x4 da4 = splat4(lDA[t]);
            float dtv = ldt[t];
            f32x4 bv0 = *(const f32x4*)&lB[t][n0];
            f32x4 bv1 = *(const f32x4*)&lB[t][n0 + 4];
#pragma unroll
            for (int pl = 0; pl < 4; ++pl) {
                f32x4 dtx = splat4(dtv * cur[tt][pl]);
                s4[pl][0] = s4[pl][0] * da4 + dtx * bv0;
                s4[pl][1] = s4[pl][1] * da4 + dtx * bv1;
            }
        }
    }

    const size_t kbase = (size_t)(bh * NCHUNK + k) * (HEADDIM * DSTATE);
#pragma unroll
    for (int pl = 0; pl < 4; ++pl) {
        size_t a = kbase + (size_t)(pg * 4 + pl) * DSTATE + n0;
        u16x8 o;
#pragma unroll
        for (int j = 0; j < 4; ++j) {
            o[j]     = f2bf(s4[pl][0][j]);
            o[4 + j] = f2bf(s4[pl][1][j]);
        }
        *(u16x8*)(Sloc + a) = o;
    }

    if (tid == 0) {
        float pr = 1.f;
#pragma unroll 8
        for (int t = 0; t < CHUNK; ++t) pr *= lDA[t];
        Pk[bh * NCHUNK + k] = pr;
    }
}

// ---------------- scan phase 2: inter-chunk prefix (bf16 I/O, f32 carry) ----
__global__ __launch_bounds__(256) void scan_phase2(
    unsigned short* __restrict__ Sloc, const float* __restrict__ Pk)
{
    int bh = blockIdx.x >> 5;
    int eo = (blockIdx.x & 31) * 256 + threadIdx.x;
    __shared__ float lP[NCHUNK];
    if (threadIdx.x < NCHUNK) lP[threadIdx.x] = Pk[bh * NCHUNK + threadIdx.x];
    __syncthreads();
    float s = 0.f;
    size_t base = (size_t)bh * NCHUNK * 8192 + eo;
#pragma unroll 8
    for (int k = 0; k < NCHUNK; ++k) {
        size_t a = base + (size_t)k * 8192;
        float f = bf2f(Sloc[a]);
        Sloc[a] = f2bf(s);
        s = s * lP[k] + f;
    }
}

// ======== chunk y kernel: 2p x 16n (VGPR<=64 verified config), bf16 seed ====
__global__ __launch_bounds__(256) void chunk_y_f32(
    const float* __restrict__ xbuf, const float* __restrict__ Bm,
    const float* __restrict__ Cm, const float* __restrict__ dtb,
    const float* __restrict__ dAb, const float* __restrict__ Dp,
    const unsigned short* __restrict__ Sini, float* __restrict__ ybuf)
{
    const int blk = blockIdx.x;
    const int k   = blk % NCHUNK;
    const int bh  = blk / NCHUNK;
    const int h   = bh % NHEADS;
    const int b   = bh / NHEADS;
    const int tid = threadIdx.x;
    const int pg  = tid >> 2;
    const int q   = tid & 3;
    const int n0  = q * 16;
    const size_t row0 = (size_t)b * SEQLEN + k * CHUNK;
    const float* xbase = xbuf + (row0 * NHEADS + h) * HEADDIM + pg * 2;
    float* ybase = ybuf + (row0 * NHEADS + h) * HEADDIM + pg * 2;

    __shared__ __align__(16) float lB[CHUNK][DSTATE];    // 16 KB
    __shared__ __align__(16) float lC[CHUNK][DSTATE];    // 16 KB
    __shared__ float lDA[CHUNK];
    __shared__ float ldt[CHUNK];

    for (int i = tid; i < CHUNK * DSTATE / 4; i += 256) {
        ((float4*)&lB[0][0])[i] = ((const float4*)(Bm + row0 * DSTATE))[i];
        ((float4*)&lC[0][0])[i] = ((const float4*)(Cm + row0 * DSTATE))[i];
    }
    if (tid < CHUNK) {
        lDA[tid] = dAb[(row0 + tid) * NHEADS + h];
        ldt[tid] = dtb[(row0 + tid) * NHEADS + h];
    }

    // seed 2p x 16n states from S_init (bf16 -> f32)
    f32x4 s4[2][4];
    const size_t kbase = (size_t)(bh * NCHUNK + k) * (HEADDIM * DSTATE);
#pragma unroll
    for (int pl = 0; pl < 2; ++pl) {
        size_t a = kbase + (size_t)(pg * 2 + pl) * DSTATE + n0;
        u16x8 v0 = *(const u16x8*)(Sini + a);
        u16x8 v1 = *(const u16x8*)(Sini + a + 8);
#pragma unroll
        for (int j = 0; j < 4; ++j) {
            s4[pl][0][j] = bf2f(v0[j]);
            s4[pl][1][j] = bf2f(v0[4 + j]);
            s4[pl][2][j] = bf2f(v1[j]);
            s4[pl][3][j] = bf2f(v1[4 + j]);
        }
    }
    const float dph = Dp[h];

    float xa[2][8], xb[2][8];
#pragma unroll
    for (int tt = 0; tt < 8; ++tt) {
        float2 v = *(const float2*)(xbase + (size_t)tt * (NHEADS * HEADDIM));
        xa[0][tt] = v.x; xa[1][tt] = v.y;
    }
    __syncthreads();

#pragma unroll
    for (int tile = 0; tile < 8; ++tile) {
        float (*cur)[8] = (tile & 1) ? xb : xa;
        float (*nxt)[8] = (tile & 1) ? xa : xb;
        if (tile < 7) {
#pragma unroll
            for (int tt = 0; tt < 8; ++tt) {
                float2 v = *(const float2*)(xbase +
                    (size_t)((tile + 1) * 8 + tt) * (NHEADS * HEADDIM));
                nxt[0][tt] = v.x; nxt[1][tt] = v.y;
            }
        }
#pragma unroll
        for (int tt = 0; tt < 8; ++tt) {
            int t = tile * 8 + tt;
            f32x4 da4 = splat4(lDA[t]);
            float dtv = ldt[t];
            f32x4 bv0 = *(const f32x4*)&lB[t][n0];
            f32x4 bv1 = *(const f32x4*)&lB[t][n0 + 4];
            f32x4 bv2 = *(const f32x4*)&lB[t][n0 + 8];
            f32x4 bv3 = *(const f32x4*)&lB[t][n0 + 12];
            f32x4 cv0 = *(const f32x4*)&lC[t][n0];
            f32x4 cv1 = *(const f32x4*)&lC[t][n0 + 4];
            f32x4 cv2 = *(const f32x4*)&lC[t][n0 + 8];
            f32x4 cv3 = *(const f32x4*)&lC[t][n0 + 12];
            float yr[2];
#pragma unroll
            for (int pl = 0; pl < 2; ++pl) {
                f32x4 dtx = splat4(dtv * cur[pl][tt]);
                f32x4 v0 = s4[pl][0] * da4 + dtx * bv0;
                f32x4 v1 = s4[pl][1] * da4 + dtx * bv1;
                f32x4 v2 = s4[pl][2] * da4 + dtx * bv2;
                f32x4 v3 = s4[pl][3] * da4 + dtx * bv3;
                s4[pl][0] = v0; s4[pl][1] = v1; s4[pl][2] = v2; s4[pl][3] = v3;
                f32x4 y4 = cv0 * v0 + cv1 * v1 + cv2 * v2 + cv3 * v3;
                float y = (y4[0] + y4[1]) + (y4[2] + y4[3]);
                y += __shfl_xor(y, 1);   // quad_perm DPP
                y += __shfl_xor(y, 2);   // quad_perm DPP
                yr[pl] = y;
            }
            if (q == 0) {
                float2 w = {yr[0] + dph * cur[0][tt], yr[1] + dph * cur[1][tt]};
                *(float2*)(ybase + (size_t)t * (NHEADS * HEADDIM)) = w;
            }
        }
    }
}

// ---------------- fallback: original monolithic scan ------------------------
#define NT 64
__global__ __launch_bounds__(256) void scan_kernel(
    const float* __restrict__ xbuf, const float* __restrict__ Bm,
    const float* __restrict__ Cm, const float* __restrict__ dtb,
    const float* __restrict__ dAb, const float* __restrict__ Dp,
    float* __restrict__ ybuf)
{
    int blk = blockIdx.x;
    int ps = blk & 7;
    int h  = (blk >> 3) % NHEADS;
    int b  = blk / (NHEADS * 8);
    int p0 = ps * 16;
    int tid = threadIdx.x;
    int pl  = tid >> 4;
    int n0  = (tid & 15) * 4;

    __shared__ __align__(16) float lB[NT][64];
    __shared__ __align__(16) float lC[NT][64];
    __shared__ __align__(16) float lDtx[NT][16];
    __shared__ float lDA[NT];
    __shared__ float lY[NT][16];

    float s0 = 0.f, s1 = 0.f, s2 = 0.f, s3 = 0.f;
    float dph = Dp[h];
    size_t rowbase = (size_t)b * SEQLEN;

    for (int t0 = 0; t0 < SEQLEN; t0 += NT) {
        for (int i = tid; i < NT * 64 / 4; i += 256) {
            ((float4*)&lB[0][0])[i] = ((const float4*)Bm)[(rowbase + t0) * 16 + i];
            ((float4*)&lC[0][0])[i] = ((const float4*)Cm)[(rowbase + t0) * 16 + i];
        }
        for (int i = tid; i < NT * 16; i += 256) {
            int t = i >> 4, pp = i & 15;
            size_t r = rowbase + t0 + t;
            lDtx[t][pp] = dtb[r * NHEADS + h] * xbuf[(r * NHEADS + h) * HEADDIM + p0 + pp];
        }
        if (tid < NT) lDA[tid] = dAb[(rowbase + t0 + tid) * NHEADS + h];
        __syncthreads();

        for (int t = 0; t < NT; ++t) {
            float da  = lDA[t];
            float dtx = lDtx[t][pl];
            const float* bp = &lB[t][n0];
            const float* cp = &lC[t][n0];
            s0 = s0 * da + dtx * bp[0];
            s1 = s1 * da + dtx * bp[1];
            s2 = s2 * da + dtx * bp[2];
            s3 = s3 * da + dtx * bp[3];
            float part = s0 * cp[0] + s1 * cp[1] + s2 * cp[2] + s3 * cp[3];
            part += __shfl_xor(part, 1);
            part += __shfl_xor(part, 2);
            part += __shfl_xor(part, 4);
            part += __shfl_xor(part, 8);
            if ((tid & 15) == 0) lY[t][pl] = part;
        }
        __syncthreads();

        for (int i = tid; i < NT * 16; i += 256) {
            int t = i >> 4, pp = i & 15;
            size_t r = rowbase + t0 + t;
            size_t gi = (r * NHEADS + h) * HEADDIM + p0 + pp;
            ybuf[gi] = lY[t][pp] + dph * xbuf[gi];
        }
        __syncthreads();
    }
}

// ---------------- gate (y * silu(z)) + RMSNorm -> bf16 (float2 path) --------
__global__ __launch_bounds__(256) void gate_rms_kernel(
    const float* __restrict__ ybuf, const float* __restrict__ zbuf,
    const float* __restrict__ norm_w, __hip_bfloat16* __restrict__ gbf)
{
    int row = blockIdx.x;
    int tid = threadIdx.x;
    const float2* y2 = (const float2*)(ybuf + (size_t)row * DINNER);
    const float2* z2 = (const float2*)(zbuf + (size_t)row * DINNER);
    const float2* nw2 = (const float2*)norm_w;
    float g[6];
    float ss = 0.f;
#pragma unroll
    for (int j = 0; j < 3; ++j) {
        int idx = tid + j * 256;
        float2 yy = y2[idx];
        float2 zz = z2[idx];
        float g0 = yy.x * (zz.x / (1.f + __expf(-zz.x)));
        float g1 = yy.y * (zz.y / (1.f + __expf(-zz.y)));
        g[j * 2 + 0] = g0;
        g[j * 2 + 1] = g1;
        ss += g0 * g0 + g1 * g1;
    }
#pragma unroll
    for (int m = 1; m < 64; m <<= 1) ss += __shfl_xor(ss, m);
    __shared__ float red[4];
    if ((tid & 63) == 0) red[tid >> 6] = ss;
    __syncthreads();
    float tot = red[0] + red[1] + red[2] + red[3];
    float scale = rsqrtf(tot * (1.f / DINNER) + 1e-5f);
#pragma unroll
    for (int j = 0; j < 3; ++j) {
        int idx = tid + j * 256;
        float2 w = nw2[idx];
        __hip_bfloat162 o;
        o.x = __float2bfloat16(g[j * 2 + 0] * scale * w.x);
        o.y = __float2bfloat16(g[j * 2 + 1] * scale * w.y);
        *(__hip_bfloat162*)(gbf + (size_t)row * DINNER + idx * 2) = o;
    }
}

// ---------------- launch ----------------
extern "C" void kernel_launch(void* const* d_in, const int* in_sizes, int n_in,
                              void* d_out, int out_size, void* d_ws, size_t ws_size,
                              hipStream_t stream)
{
    const float* u       = (const float*)d_in[0];
    const float* W_in    = (const float*)d_in[1];
    const float* conv_w  = (const float*)d_in[2];
    const float* conv_b  = (const float*)d_in[3];
    const float* dt_bias = (const float*)d_in[4];
    const float* A_log   = (const float*)d_in[5];
    const float* Dp      = (const float*)d_in[6];
    const float* norm_w  = (const float*)d_in[7];
    const float* W_out   = (const float*)d_in[8];
    float* out = (float*)d_out;

    char* ws = (char*)d_ws;
    size_t off = 0;
    auto alloc = [&](size_t bytes) {
        char* p = ws + off;
        off += (bytes + 255) & ~(size_t)255;
        return p;
    };
    __hip_bfloat16* ubf  = (__hip_bfloat16*)alloc((size_t)ROWS * DMODEL * 2);
    __hip_bfloat16* W1bf = (__hip_bfloat16*)alloc((size_t)NPAD1 * DMODEL * 2);
    __hip_bfloat16* W2bf = (__hip_bfloat16*)alloc((size_t)DMODEL * DINNER * 2);
    float* zbuf  = (float*)alloc((size_t)ROWS * DINNER * 4);   // z columns
    float* xbcdt = (float*)alloc((size_t)ROWS * DXBC * 4);     // xBC + dt columns
    float* xbuf = (float*)alloc((size_t)ROWS * DINNER * 4);
    float* Bmb  = (float*)alloc((size_t)ROWS * DSTATE * 4);
    float* Cmb  = (float*)alloc((size_t)ROWS * DSTATE * 4);
    float* dtb  = (float*)alloc((size_t)ROWS * NHEADS * 4);
    float* dAb  = (float*)alloc((size_t)ROWS * NHEADS * 4);
    float* ybuf = (float*)alloc((size_t)ROWS * DINNER * 4);
    float* Pkb  = (float*)alloc((size_t)BATCH * NHEADS * NCHUNK * 4);
    __hip_bfloat16* gbf = (__hip_bfloat16*)xbuf;  // reuse: xbuf dead after scan
    // ALIAS: xbcdt (54.9 MB) dead after conv+dt; bf16 Sloc (25.2 MB) reuses it.
    unsigned short* Sloc = (unsigned short*)xbcdt;
    bool chunked = (off <= ws_size);

    // fused prep (cvt u, pad+cvt W_in, cvt W_out)
    {
        int ntot = (NPREP1 + NPREP2 + NPREP3) / 4;
        prep_kernel<<<(ntot + 255) / 256, 256, 0, stream>>>(
            u, W_in, W_out, ubf, W1bf, W2bf);
    }

    // GEMM1: single pass, per-tile routed output (z | xBCdt)
    gemm1_fused<<<dim3(ROWS / 128, NPAD1 / 128), 256, 0, stream>>>(
        ubf, W1bf, zbuf, xbcdt);

    // conv + fused dt/dA (dt columns handled by the tail threads)
    conv_kernel<<<dim3((DXBC + 255) / 256, ROWS / CROWS), 256, 0, stream>>>(
        xbcdt, conv_w, conv_b, dt_bias, A_log, xbuf, Bmb, Cmb, dtb, dAb);

    if (chunked) {
        chunk_state_f32<<<BATCH * NHEADS * NCHUNK, 256, 0, stream>>>(
            xbuf, Bmb, dtb, dAb, Sloc, Pkb);
        scan_phase2<<<BATCH * NHEADS * 32, 256, 0, stream>>>(Sloc, Pkb);
        chunk_y_f32<<<BATCH * NHEADS * NCHUNK, 256, 0, stream>>>(
            xbuf, Bmb, Cmb, dtb, dAb, Dp, Sloc, ybuf);
    } else {
        scan_kernel<<<BATCH * NHEADS * 8, 256, 0, stream>>>(
            xbuf, Bmb, Cmb, dtb, dAb, Dp, ybuf);
    }

    gate_rms_kernel<<<ROWS, 256, 0, stream>>>(ybuf, zbuf, norm_w, gbf);

    gemm_bf16_nt<<<dim3(ROWS / 128, DMODEL / 128), 256, 0, stream>>>(
        gbf, W2bf, out, ROWS, DMODEL, DINNER, DMODEL);
}

// Round 18
// 262.757 us; speedup vs baseline: 1.1618x; 1.0616x over previous
//
#include <hip/hip_runtime.h>
#include <hip/hip_bf16.h>
#include <stdint.h>

#define BATCH   2
#define SEQLEN  4096
#define DMODEL  768
#define DSTATE  64
#define DCONV   4
#define HEADDIM 128
#define NHEADS  12
#define DINNER  1536
#define DINPROJ 3212
#define CONVDIM 1664
#define DXBC    1676            // CONVDIM + NHEADS (xBC + dt columns)
#define NPAD1   3328            // 26*128, padded rows of W_in (bf16 copy)
#define ROWS    (BATCH*SEQLEN)  // 8192
#define CHUNK   64
#define NCHUNK  (SEQLEN/CHUNK)  // 64
#define CROWS   8               // rows per conv block
#define TBUF    4096            // GEMM LDS buffer stride (elements) = 128*32

typedef __bf16 bf16x8 __attribute__((ext_vector_type(8)));
typedef float  f32x4  __attribute__((ext_vector_type(4)));
typedef unsigned short u16x8 __attribute__((ext_vector_type(8)));
typedef unsigned short u16x4 __attribute__((ext_vector_type(4)));
typedef unsigned short u16x2 __attribute__((ext_vector_type(2)));

__device__ __forceinline__ f32x4 splat4(float v) { return (f32x4){v, v, v, v}; }

__device__ __forceinline__ unsigned short f2bf(float f) {
    __hip_bfloat16 h = __float2bfloat16(f);
    return *reinterpret_cast<unsigned short*>(&h);
}
__device__ __forceinline__ float bf2f(unsigned short u) {
    return __uint_as_float(((unsigned int)u) << 16);
}

__device__ __forceinline__ void load_lds16(const void* g, void* l) {
    __builtin_amdgcn_global_load_lds(
        (const __attribute__((address_space(1))) unsigned int*)g,
        (__attribute__((address_space(3))) unsigned int*)l, 16, 0, 0);
}

// ---------------- fused prep: cvt u, pad+cvt W_in, cvt W_out ----------------
#define NPREP1 (ROWS*DMODEL)
#define NPREP2 (NPAD1*DMODEL)
#define NPREP3 (DMODEL*DINNER)
__global__ void prep_kernel(const float* __restrict__ u,
                            const float* __restrict__ W_in,
                            const float* __restrict__ W_out,
                            __hip_bfloat16* __restrict__ ubf,
                            __hip_bfloat16* __restrict__ W1bf,
                            __hip_bfloat16* __restrict__ W2bf)
{
    int i = (blockIdx.x * 256 + threadIdx.x) * 4;
    if (i < NPREP1) {
        float4 v = *(const float4*)(u + i);
        ubf[i + 0] = __float2bfloat16(v.x);
        ubf[i + 1] = __float2bfloat16(v.y);
        ubf[i + 2] = __float2bfloat16(v.z);
        ubf[i + 3] = __float2bfloat16(v.w);
    } else if (i < NPREP1 + NPREP2) {
        int j = i - NPREP1;
        int r = j / DMODEL;                 // 4-elem group never crosses rows
        if (r < DINPROJ) {
            float4 v = *(const float4*)(W_in + j);
            W1bf[j + 0] = __float2bfloat16(v.x);
            W1bf[j + 1] = __float2bfloat16(v.y);
            W1bf[j + 2] = __float2bfloat16(v.z);
            W1bf[j + 3] = __float2bfloat16(v.w);
        } else {
            __hip_bfloat16 z = __float2bfloat16(0.f);
            W1bf[j + 0] = z; W1bf[j + 1] = z; W1bf[j + 2] = z; W1bf[j + 3] = z;
        }
    } else if (i < NPREP1 + NPREP2 + NPREP3) {
        int j = i - NPREP1 - NPREP2;
        float4 v = *(const float4*)(W_out + j);
        W2bf[j + 0] = __float2bfloat16(v.x);
        W2bf[j + 1] = __float2bfloat16(v.y);
        W2bf[j + 2] = __float2bfloat16(v.z);
        W2bf[j + 3] = __float2bfloat16(v.w);
    }
}

// ---------------- bf16 MFMA GEMM (double-buffered, swizzled LDS) ------------
__global__ __launch_bounds__(256) void gemm_bf16_nt(
    const __hip_bfloat16* __restrict__ A,
    const __hip_bfloat16* __restrict__ Bt,
    float* __restrict__ C,
    int M, int Nreal, int K, int ldc)
{
    __shared__ __align__(16) __hip_bfloat16 As[2 * TBUF];
    __shared__ __align__(16) __hip_bfloat16 Bs[2 * TBUF];
    const int tid  = threadIdx.x;
    const int lane = tid & 63;
    const int wave = tid >> 6;
    const int wm   = wave >> 1;
    const int wn   = wave & 1;
    const int tm   = blockIdx.x * 128;
    const int tn   = blockIdx.y * 128;

    f32x4 acc[4][4] = {};

    const int lrow = tid >> 2;
    const int lk8s = ((tid & 3) * 8) ^ (((tid >> 3) & 3) << 3);
    const __hip_bfloat16* gA0 = A  + (size_t)(tm + lrow)      * K + lk8s;
    const __hip_bfloat16* gA1 = A  + (size_t)(tm + lrow + 64) * K + lk8s;
    const __hip_bfloat16* gB0 = Bt + (size_t)(tn + lrow)      * K + lk8s;
    const __hip_bfloat16* gB1 = Bt + (size_t)(tn + lrow + 64) * K + lk8s;

    const int fr  = lane & 15;
    const int fks = ((lane >> 4) * 8) ^ (((lane >> 1) & 3) << 3);

    load_lds16(gA0, As + tid * 8);
    load_lds16(gA1, As + tid * 8 + 2048);
    load_lds16(gB0, Bs + tid * 8);
    load_lds16(gB1, Bs + tid * 8 + 2048);
    __syncthreads();

    int bufo = 0;
    for (int kk = 0; kk < K; kk += 32) {
        const int nbufo = bufo ^ TBUF;
        if (kk + 32 < K) {
            load_lds16(gA0 + kk + 32, As + nbufo + tid * 8);
            load_lds16(gA1 + kk + 32, As + nbufo + tid * 8 + 2048);
            load_lds16(gB0 + kk + 32, Bs + nbufo + tid * 8);
            load_lds16(gB1 + kk + 32, Bs + nbufo + tid * 8 + 2048);
        }
        bf16x8 af[4], bfr[4];
#pragma unroll
        for (int i = 0; i < 4; ++i) {
            af[i]  = *(const bf16x8*)(As + bufo + (wm * 64 + i * 16 + fr) * 32 + fks);
            bfr[i] = *(const bf16x8*)(Bs + bufo + (wn * 64 + i * 16 + fr) * 32 + fks);
        }
#pragma unroll
        for (int mi = 0; mi < 4; ++mi)
#pragma unroll
            for (int ni = 0; ni < 4; ++ni)
                acc[mi][ni] = __builtin_amdgcn_mfma_f32_16x16x32_bf16(
                    af[mi], bfr[ni], acc[mi][ni], 0, 0, 0);
        __syncthreads();
        bufo = nbufo;
    }

    const int rq = (lane >> 4) * 4;
#pragma unroll
    for (int mi = 0; mi < 4; ++mi) {
#pragma unroll
        for (int ni = 0; ni < 4; ++ni) {
            int col = tn + wn * 64 + ni * 16 + fr;
            if (col < Nreal) {
                size_t rbase = (size_t)(tm + wm * 64 + mi * 16 + rq) * ldc + col;
#pragma unroll
                for (int j = 0; j < 4; ++j)
                    C[rbase + (size_t)j * ldc] = acc[mi][ni][j];
            }
        }
    }
}

// ---------------- GEMM1 fused (dbuf, swizzled; z -> bf16, xbcdt -> f32) -----
__global__ __launch_bounds__(256) void gemm1_fused(
    const __hip_bfloat16* __restrict__ A,
    const __hip_bfloat16* __restrict__ Bt,
    __hip_bfloat16* __restrict__ Cz,   // (ROWS, DINNER) bf16
    float* __restrict__ Cx)            // (ROWS, DXBC)  f32
{
    __shared__ __align__(16) __hip_bfloat16 As[2 * TBUF];
    __shared__ __align__(16) __hip_bfloat16 Bs[2 * TBUF];
    const int tid  = threadIdx.x;
    const int lane = tid & 63;
    const int wave = tid >> 6;
    const int wm   = wave >> 1;
    const int wn   = wave & 1;
    const int tm   = blockIdx.x * 128;
    const int tn   = blockIdx.y * 128;
    const int K    = DMODEL;

    f32x4 acc[4][4] = {};

    const int lrow = tid >> 2;
    const int lk8s = ((tid & 3) * 8) ^ (((tid >> 3) & 3) << 3);
    const __hip_bfloat16* gA0 = A  + (size_t)(tm + lrow)      * K + lk8s;
    const __hip_bfloat16* gA1 = A  + (size_t)(tm + lrow + 64) * K + lk8s;
    const __hip_bfloat16* gB0 = Bt + (size_t)(tn + lrow)      * K + lk8s;
    const __hip_bfloat16* gB1 = Bt + (size_t)(tn + lrow + 64) * K + lk8s;

    const int fr  = lane & 15;
    const int fks = ((lane >> 4) * 8) ^ (((lane >> 1) & 3) << 3);

    load_lds16(gA0, As + tid * 8);
    load_lds16(gA1, As + tid * 8 + 2048);
    load_lds16(gB0, Bs + tid * 8);
    load_lds16(gB1, Bs + tid * 8 + 2048);
    __syncthreads();

    int bufo = 0;
    for (int kk = 0; kk < K; kk += 32) {
        const int nbufo = bufo ^ TBUF;
        if (kk + 32 < K) {
            load_lds16(gA0 + kk + 32, As + nbufo + tid * 8);
            load_lds16(gA1 + kk + 32, As + nbufo + tid * 8 + 2048);
            load_lds16(gB0 + kk + 32, Bs + nbufo + tid * 8);
            load_lds16(gB1 + kk + 32, Bs + nbufo + tid * 8 + 2048);
        }
        bf16x8 af[4], bfr[4];
#pragma unroll
        for (int i = 0; i < 4; ++i) {
            af[i]  = *(const bf16x8*)(As + bufo + (wm * 64 + i * 16 + fr) * 32 + fks);
            bfr[i] = *(const bf16x8*)(Bs + bufo + (wn * 64 + i * 16 + fr) * 32 + fks);
        }
#pragma unroll
        for (int mi = 0; mi < 4; ++mi)
#pragma unroll
            for (int ni = 0; ni < 4; ++ni)
                acc[mi][ni] = __builtin_amdgcn_mfma_f32_16x16x32_bf16(
                    af[mi], bfr[ni], acc[mi][ni], 0, 0, 0);
        __syncthreads();
        bufo = nbufo;
    }

    const int rq = (lane >> 4) * 4;
    if (tn < DINNER) {
#pragma unroll
        for (int mi = 0; mi < 4; ++mi)
#pragma unroll
            for (int ni = 0; ni < 4; ++ni) {
                int col = tn + wn * 64 + ni * 16 + fr;
                size_t rbase = (size_t)(tm + wm * 64 + mi * 16 + rq) * DINNER + col;
#pragma unroll
                for (int j = 0; j < 4; ++j)
                    Cz[rbase + (size_t)j * DINNER] = __float2bfloat16(acc[mi][ni][j]);
            }
    } else {
#pragma unroll
        for (int mi = 0; mi < 4; ++mi)
#pragma unroll
            for (int ni = 0; ni < 4; ++ni) {
                int col = tn - DINNER + wn * 64 + ni * 16 + fr;
                if (col < DXBC) {
                    size_t rbase = (size_t)(tm + wm * 64 + mi * 16 + rq) * DXBC + col;
#pragma unroll
                    for (int j = 0; j < 4; ++j)
                        Cx[rbase + (size_t)j * DXBC] = acc[mi][ni][j];
                }
            }
    }
}

// ---------------- conv (8 rows/block, rolling window) + fused dt/dA ---------
// x output now bf16.
__global__ void conv_kernel(const float* __restrict__ xbcdt,
                            const float* __restrict__ convw,
                            const float* __restrict__ convb,
                            const float* __restrict__ dt_bias,
                            const float* __restrict__ A_log,
                            __hip_bfloat16* __restrict__ xbuf,
                            float* __restrict__ Bm,
                            float* __restrict__ Cm,
                            float* __restrict__ dtb,
                            float* __restrict__ dAb)
{
    int c = blockIdx.x * 256 + threadIdx.x;
    size_t row0 = (size_t)blockIdx.y * CROWS;
    if (c < CONVDIM) {
        int l0 = (int)(row0 & (SEQLEN - 1));
        float w0 = convw[c * 4 + 0];
        float w1 = convw[c * 4 + 1];
        float w2 = convw[c * 4 + 2];
        float w3 = convw[c * 4 + 3];
        float bias = convb[c];
        const float* src = xbcdt + row0 * DXBC + c;
        float x0 = (l0 >= 3) ? src[-3 * DXBC] : 0.f;
        float x1 = (l0 >= 2) ? src[-2 * DXBC] : 0.f;
        float x2 = (l0 >= 1) ? src[-1 * DXBC] : 0.f;
#pragma unroll
        for (int r = 0; r < CROWS; ++r) {
            float x3 = src[(size_t)r * DXBC];
            float acc = bias + x0 * w0 + x1 * w1 + x2 * w2 + x3 * w3;
            float v = acc / (1.f + __expf(-acc));
            size_t row = row0 + r;
            if (c < DINNER)               xbuf[row * DINNER + c] = __float2bfloat16(v);
            else if (c < DINNER + DSTATE) Bm[row * DSTATE + (c - DINNER)] = v;
            else                          Cm[row * DSTATE + (c - DINNER - DSTATE)] = v;
            x0 = x1; x1 = x2; x2 = x3;
        }
    } else if (c < DXBC) {
        int h = c - CONVDIM;
        float bias = dt_bias[h];
        float A = -__expf(A_log[h]);
        const float* src = xbcdt + row0 * DXBC + c;
#pragma unroll
        for (int r = 0; r < CROWS; ++r) {
            float v = src[(size_t)r * DXBC] + bias;
            float dt = (v > 20.f) ? v : log1pf(__expf(v));
            size_t row = row0 + r;
            dtb[row * NHEADS + h] = dt;
            dAb[row * NHEADS + h] = __expf(dt * A);
        }
    }
}

// ======== chunk state kernel: 4p x 8n, bf16 x in, bf16 state out ============
__global__ __launch_bounds__(256) void chunk_state_f32(
    const __hip_bfloat16* __restrict__ xbuf, const float* __restrict__ Bm,
    const float* __restrict__ dtb, const float* __restrict__ dAb,
    unsigned short* __restrict__ Sloc, float* __restrict__ Pk)
{
    const int blk = blockIdx.x;
    const int k   = blk % NCHUNK;
    const int bh  = blk / NCHUNK;
    const int h   = bh % NHEADS;
    const int b   = bh / NHEADS;
    const int tid = threadIdx.x;
    const int pg  = tid >> 3;
    const int n0  = (tid & 7) * 8;
    const size_t row0 = (size_t)b * SEQLEN + k * CHUNK;
    const __hip_bfloat16* xbase = xbuf + (row0 * NHEADS + h) * HEADDIM + pg * 4;

    __shared__ __align__(16) float lB[CHUNK][DSTATE];    // 16 KB
    __shared__ float lDA[CHUNK];
    __shared__ float ldt[CHUNK];

    for (int i = tid; i < CHUNK * DSTATE / 4; i += 256)
        ((float4*)&lB[0][0])[i] = ((const float4*)(Bm + row0 * DSTATE))[i];
    if (tid < CHUNK) {
        lDA[tid] = dAb[(row0 + tid) * NHEADS + h];
        ldt[tid] = dtb[(row0 + tid) * NHEADS + h];
    }
    __syncthreads();

    f32x4 s4[4][2] = {};
    u16x4 xt0[4], xt1[4];

#pragma unroll
    for (int tt = 0; tt < 4; ++tt)
        xt0[tt] = *(const u16x4*)(xbase + (size_t)tt * (NHEADS * HEADDIM));

#pragma unroll
    for (int tile = 0; tile < 16; ++tile) {
        u16x4* cur = (tile & 1) ? xt1 : xt0;
        u16x4* nxt = (tile & 1) ? xt0 : xt1;
        if (tile < 15) {
#pragma unroll
            for (int tt = 0; tt < 4; ++tt)
                nxt[tt] = *(const u16x4*)(xbase +
                    (size_t)((tile + 1) * 4 + tt) * (NHEADS * HEADDIM));
        }
#pragma unroll
        for (int tt = 0; tt < 4; ++tt) {
            int t = tile * 4 + tt;
            f32x4 da4 = splat4(lDA[t]);
            float dtv = ldt[t];
            f32x4 bv0 = *(const f32x4*)&lB[t][n0];
            f32x4 bv1 = *(const f32x4*)&lB[t][n0 + 4];
#pragma unroll
            for (int pl = 0; pl < 4; ++pl) {
                f32x4 dtx = splat4(dtv * bf2f(cur[tt][pl]));
                s4[pl][0] = s4[pl][0] * da4 + dtx * bv0;
                s4[pl][1] = s4[pl][1] * da4 + dtx * bv1;
            }
        }
    }

    const size_t kbase = (size_t)(bh * NCHUNK + k) * (HEADDIM * DSTATE);
#pragma unroll
    for (int pl = 0; pl < 4; ++pl) {
        size_t a = kbase + (size_t)(pg * 4 + pl) * DSTATE + n0;
        u16x8 o;
#pragma unroll
        for (int j = 0; j < 4; ++j) {
            o[j]     = f2bf(s4[pl][0][j]);
            o[4 + j] = f2bf(s4[pl][1][j]);
        }
        *(u16x8*)(Sloc + a) = o;
    }

    if (tid == 0) {
        float pr = 1.f;
#pragma unroll 8
        for (int t = 0; t < CHUNK; ++t) pr *= lDA[t];
        Pk[bh * NCHUNK + k] = pr;
    }
}

// ---------------- scan phase 2: inter-chunk prefix (bf16 I/O, f32 carry) ----
__global__ __launch_bounds__(256) void scan_phase2(
    unsigned short* __restrict__ Sloc, const float* __restrict__ Pk)
{
    int bh = blockIdx.x >> 5;
    int eo = (blockIdx.x & 31) * 256 + threadIdx.x;
    __shared__ float lP[NCHUNK];
    if (threadIdx.x < NCHUNK) lP[threadIdx.x] = Pk[bh * NCHUNK + threadIdx.x];
    __syncthreads();
    float s = 0.f;
    size_t base = (size_t)bh * NCHUNK * 8192 + eo;
#pragma unroll 8
    for (int k = 0; k < NCHUNK; ++k) {
        size_t a = base + (size_t)k * 8192;
        float f = bf2f(Sloc[a]);
        Sloc[a] = f2bf(s);
        s = s * lP[k] + f;
    }
}

// ======== chunk y kernel: 2p x 16n (VGPR<=64), bf16 x/y/seed ================
__global__ __launch_bounds__(256) void chunk_y_f32(
    const __hip_bfloat16* __restrict__ xbuf, const float* __restrict__ Bm,
    const float* __restrict__ Cm, const float* __restrict__ dtb,
    const float* __restrict__ dAb, const float* __restrict__ Dp,
    const unsigned short* __restrict__ Sini, __hip_bfloat16* __restrict__ ybuf)
{
    const int blk = blockIdx.x;
    const int k   = blk % NCHUNK;
    const int bh  = blk / NCHUNK;
    const int h   = bh % NHEADS;
    const int b   = bh / NHEADS;
    const int tid = threadIdx.x;
    const int pg  = tid >> 2;
    const int q   = tid & 3;
    const int n0  = q * 16;
    const size_t row0 = (size_t)b * SEQLEN + k * CHUNK;
    const __hip_bfloat16* xbase = xbuf + (row0 * NHEADS + h) * HEADDIM + pg * 2;
    __hip_bfloat16* ybase = ybuf + (row0 * NHEADS + h) * HEADDIM + pg * 2;

    __shared__ __align__(16) float lB[CHUNK][DSTATE];    // 16 KB
    __shared__ __align__(16) float lC[CHUNK][DSTATE];    // 16 KB
    __shared__ float lDA[CHUNK];
    __shared__ float ldt[CHUNK];

    for (int i = tid; i < CHUNK * DSTATE / 4; i += 256) {
        ((float4*)&lB[0][0])[i] = ((const float4*)(Bm + row0 * DSTATE))[i];
        ((float4*)&lC[0][0])[i] = ((const float4*)(Cm + row0 * DSTATE))[i];
    }
    if (tid < CHUNK) {
        lDA[tid] = dAb[(row0 + tid) * NHEADS + h];
        ldt[tid] = dtb[(row0 + tid) * NHEADS + h];
    }

    // seed 2p x 16n states from S_init (bf16 -> f32)
    f32x4 s4[2][4];
    const size_t kbase = (size_t)(bh * NCHUNK + k) * (HEADDIM * DSTATE);
#pragma unroll
    for (int pl = 0; pl < 2; ++pl) {
        size_t a = kbase + (size_t)(pg * 2 + pl) * DSTATE + n0;
        u16x8 v0 = *(const u16x8*)(Sini + a);
        u16x8 v1 = *(const u16x8*)(Sini + a + 8);
#pragma unroll
        for (int j = 0; j < 4; ++j) {
            s4[pl][0][j] = bf2f(v0[j]);
            s4[pl][1][j] = bf2f(v0[4 + j]);
            s4[pl][2][j] = bf2f(v1[j]);
            s4[pl][3][j] = bf2f(v1[4 + j]);
        }
    }
    const float dph = Dp[h];

    u16x2 xa[8], xb[8];
#pragma unroll
    for (int tt = 0; tt < 8; ++tt)
        xa[tt] = *(const u16x2*)(xbase + (size_t)tt * (NHEADS * HEADDIM));
    __syncthreads();

#pragma unroll
    for (int tile = 0; tile < 8; ++tile) {
        u16x2* cur = (tile & 1) ? xb : xa;
        u16x2* nxt = (tile & 1) ? xa : xb;
        if (tile < 7) {
#pragma unroll
            for (int tt = 0; tt < 8; ++tt)
                nxt[tt] = *(const u16x2*)(xbase +
                    (size_t)((tile + 1) * 8 + tt) * (NHEADS * HEADDIM));
        }
#pragma unroll
        for (int tt = 0; tt < 8; ++tt) {
            int t = tile * 8 + tt;
            f32x4 da4 = splat4(lDA[t]);
            float dtv = ldt[t];
            float xv0 = bf2f(cur[tt][0]);
            float xv1 = bf2f(cur[tt][1]);
            f32x4 bv0 = *(const f32x4*)&lB[t][n0];
            f32x4 bv1 = *(const f32x4*)&lB[t][n0 + 4];
            f32x4 bv2 = *(const f32x4*)&lB[t][n0 + 8];
            f32x4 bv3 = *(const f32x4*)&lB[t][n0 + 12];
            f32x4 cv0 = *(const f32x4*)&lC[t][n0];
            f32x4 cv1 = *(const f32x4*)&lC[t][n0 + 4];
            f32x4 cv2 = *(const f32x4*)&lC[t][n0 + 8];
            f32x4 cv3 = *(const f32x4*)&lC[t][n0 + 12];
            float yr[2];
#pragma unroll
            for (int pl = 0; pl < 2; ++pl) {
                f32x4 dtx = splat4(dtv * (pl ? xv1 : xv0));
                f32x4 v0 = s4[pl][0] * da4 + dtx * bv0;
                f32x4 v1 = s4[pl][1] * da4 + dtx * bv1;
                f32x4 v2 = s4[pl][2] * da4 + dtx * bv2;
                f32x4 v3 = s4[pl][3] * da4 + dtx * bv3;
                s4[pl][0] = v0; s4[pl][1] = v1; s4[pl][2] = v2; s4[pl][3] = v3;
                f32x4 y4 = cv0 * v0 + cv1 * v1 + cv2 * v2 + cv3 * v3;
                float y = (y4[0] + y4[1]) + (y4[2] + y4[3]);
                y += __shfl_xor(y, 1);   // quad_perm DPP
                y += __shfl_xor(y, 2);   // quad_perm DPP
                yr[pl] = y;
            }
            if (q == 0) {
                u16x2 w = {f2bf(yr[0] + dph * xv0), f2bf(yr[1] + dph * xv1)};
                *(u16x2*)(ybase + (size_t)t * (NHEADS * HEADDIM)) = w;
            }
        }
    }
}

// ---------------- gate (y * silu(z)) + RMSNorm -> bf16 (bf16 inputs) --------
__global__ __launch_bounds__(256) void gate_rms_kernel(
    const __hip_bfloat16* __restrict__ ybuf, const __hip_bfloat16* __restrict__ zbuf,
    const float* __restrict__ norm_w, __hip_bfloat16* __restrict__ gbf)
{
    int row = blockIdx.x;
    int tid = threadIdx.x;
    const u16x2* y2 = (const u16x2*)(ybuf + (size_t)row * DINNER);
    const u16x2* z2 = (const u16x2*)(zbuf + (size_t)row * DINNER);
    const float2* nw2 = (const float2*)norm_w;
    float g[6];
    float ss = 0.f;
#pragma unroll
    for (int j = 0; j < 3; ++j) {
        int idx = tid + j * 256;
        u16x2 yy = y2[idx];
        u16x2 zz = z2[idx];
        float z0 = bf2f(zz[0]), z1 = bf2f(zz[1]);
        float g0 = bf2f(yy[0]) * (z0 / (1.f + __expf(-z0)));
        float g1 = bf2f(yy[1]) * (z1 / (1.f + __expf(-z1)));
        g[j * 2 + 0] = g0;
        g[j * 2 + 1] = g1;
        ss += g0 * g0 + g1 * g1;
    }
#pragma unroll
    for (int m = 1; m < 64; m <<= 1) ss += __shfl_xor(ss, m);
    __shared__ float red[4];
    if ((tid & 63) == 0) red[tid >> 6] = ss;
    __syncthreads();
    float tot = red[0] + red[1] + red[2] + red[3];
    float scale = rsqrtf(tot * (1.f / DINNER) + 1e-5f);
#pragma unroll
    for (int j = 0; j < 3; ++j) {
        int idx = tid + j * 256;
        float2 w = nw2[idx];
        __hip_bfloat162 o;
        o.x = __float2bfloat16(g[j * 2 + 0] * scale * w.x);
        o.y = __float2bfloat16(g[j * 2 + 1] * scale * w.y);
        *(__hip_bfloat162*)(gbf + (size_t)row * DINNER + idx * 2) = o;
    }
}

// ---------------- launch ----------------
extern "C" void kernel_launch(void* const* d_in, const int* in_sizes, int n_in,
                              void* d_out, int out_size, void* d_ws, size_t ws_size,
                              hipStream_t stream)
{
    const float* u       = (const float*)d_in[0];
    const float* W_in    = (const float*)d_in[1];
    const float* conv_w  = (const float*)d_in[2];
    const float* conv_b  = (const float*)d_in[3];
    const float* dt_bias = (const float*)d_in[4];
    const float* A_log   = (const float*)d_in[5];
    const float* Dp      = (const float*)d_in[6];
    const float* norm_w  = (const float*)d_in[7];
    const float* W_out   = (const float*)d_in[8];
    float* out = (float*)d_out;

    char* ws = (char*)d_ws;
    size_t off = 0;
    auto alloc = [&](size_t bytes) {
        char* p = ws + off;
        off += (bytes + 255) & ~(size_t)255;
        return p;
    };
    __hip_bfloat16* ubf  = (__hip_bfloat16*)alloc((size_t)ROWS * DMODEL * 2);
    __hip_bfloat16* W1bf = (__hip_bfloat16*)alloc((size_t)NPAD1 * DMODEL * 2);
    __hip_bfloat16* W2bf = (__hip_bfloat16*)alloc((size_t)DMODEL * DINNER * 2);
    __hip_bfloat16* zbuf = (__hip_bfloat16*)alloc((size_t)ROWS * DINNER * 2);  // z (bf16)
    float* xbcdt = (float*)alloc((size_t)ROWS * DXBC * 4);     // xBC + dt columns
    __hip_bfloat16* xbuf = (__hip_bfloat16*)alloc((size_t)ROWS * DINNER * 2);  // x (bf16)
    float* Bmb  = (float*)alloc((size_t)ROWS * DSTATE * 4);
    float* Cmb  = (float*)alloc((size_t)ROWS * DSTATE * 4);
    float* dtb  = (float*)alloc((size_t)ROWS * NHEADS * 4);
    float* dAb  = (float*)alloc((size_t)ROWS * NHEADS * 4);
    __hip_bfloat16* ybuf = (__hip_bfloat16*)alloc((size_t)ROWS * DINNER * 2);  // y (bf16)
    float* Pkb  = (float*)alloc((size_t)BATCH * NHEADS * NCHUNK * 4);
    __hip_bfloat16* gbf = (__hip_bfloat16*)alloc((size_t)ROWS * DINNER * 2);
    // ALIAS: xbcdt (54.9 MB) dead after conv+dt; bf16 Sloc (25.2 MB) reuses it.
    unsigned short* Sloc = (unsigned short*)xbcdt;
    (void)ws_size;

    // fused prep (cvt u, pad+cvt W_in, cvt W_out)
    {
        int ntot = (NPREP1 + NPREP2 + NPREP3) / 4;
        prep_kernel<<<(ntot + 255) / 256, 256, 0, stream>>>(
            u, W_in, W_out, ubf, W1bf, W2bf);
    }

    // GEMM1: single pass, per-tile routed output (z bf16 | xBCdt f32)
    gemm1_fused<<<dim3(ROWS / 128, NPAD1 / 128), 256, 0, stream>>>(
        ubf, W1bf, zbuf, xbcdt);

    // conv + fused dt/dA (dt columns handled by the tail threads)
    conv_kernel<<<dim3((DXBC + 255) / 256, ROWS / CROWS), 256, 0, stream>>>(
        xbcdt, conv_w, conv_b, dt_bias, A_log, xbuf, Bmb, Cmb, dtb, dAb);

    chunk_state_f32<<<BATCH * NHEADS * NCHUNK, 256, 0, stream>>>(
        xbuf, Bmb, dtb, dAb, Sloc, Pkb);
    scan_phase2<<<BATCH * NHEADS * 32, 256, 0, stream>>>(Sloc, Pkb);
    chunk_y_f32<<<BATCH * NHEADS * NCHUNK, 256, 0, stream>>>(
        xbuf, Bmb, Cmb, dtb, dAb, Dp, Sloc, ybuf);

    gate_rms_kernel<<<ROWS, 256, 0, stream>>>(ybuf, zbuf, norm_w, gbf);

    gemm_bf16_nt<<<dim3(ROWS / 128, DMODEL / 128), 256, 0, stream>>>(
        gbf, W2bf, out, ROWS, DMODEL, DINNER, DMODEL);
}